// Round 4
// baseline (265.306 us; speedup 1.0000x reference)
//
#include <hip/hip_runtime.h>

#define B_ 512
#define D_ 512
#define L_ 32
#define H_ 300
#define NT 19       // 16-col n-tiles of H
#define NS 10       // 32-k steps over K=300 (zero-padded weights beyond 300)
#define G1S 312     // g1 LDS row stride (ushorts): rows 16B-aligned, bank-friendly

typedef unsigned short ushort_t;
typedef __bf16 bf16x8 __attribute__((ext_vector_type(8)));
typedef float f32x4 __attribute__((ext_vector_type(4)));

__device__ __forceinline__ float bf2f(unsigned int hi16) {
    return __uint_as_float(hi16 << 16);
}
__device__ __forceinline__ ushort_t f2bf(float f) {
    unsigned int u = __float_as_uint(f);
    u += 0x7fffu + ((u >> 16) & 1u);   // RNE (finite inputs)
    return (ushort_t)(u >> 16);
}
__device__ __forceinline__ unsigned int pack2(float a, float b) {
    return (unsigned int)f2bf(a) | ((unsigned int)f2bf(b) << 16);
}

union B8 { ushort_t u[8]; uint4 q; bf16x8 v; };

// ---------------- prep: swizzle weights into MFMA B-fragment layout ----------------
// frag elem i of lane l = B[k = 32*s + 8*(l>>4) + i][n = 16*nt + (l&15)]; OOR -> 0
// decoder weights: single bf16; encoder weights: hi/lo bf16 pair (split-fp32)
__global__ __launch_bounds__(64) void prep_kernel(
        const float* __restrict__ gw1, const float* __restrict__ gw2,
        const float* __restrict__ qw1, const float* __restrict__ qw2,
        const float* __restrict__ zmw, const float* __restrict__ zlw,
        ushort_t* __restrict__ gw1f, ushort_t* __restrict__ gw2f,
        ushort_t* __restrict__ w1hi, ushort_t* __restrict__ w1lo,
        ushort_t* __restrict__ w2hi, ushort_t* __restrict__ w2lo,
        ushort_t* __restrict__ w3hi, ushort_t* __restrict__ w3lo) {
    int blk = blockIdx.x;
    int l = threadIdx.x, grp = l >> 4, li = l & 15;
    if (blk < 209) {    // decoder weights, single bf16
        const float* src; int K, nt, s; ushort_t* dst;
        if (blk < 19) { nt = blk; s = 0; src = gw1; K = 32; dst = gw1f + (nt * 64 + l) * 8; }
        else { int i = blk - 19; nt = i / 10; s = i % 10; src = gw2; K = 300;
               dst = gw2f + ((nt * 10 + s) * 64 + l) * 8; }
        int n = nt * 16 + li;
        B8 V;
        #pragma unroll
        for (int i = 0; i < 8; ++i) {
            int k = 32 * s + 8 * grp + i;
            V.u[i] = f2bf((k < K && n < H_) ? src[k * H_ + n] : 0.f);
        }
        *reinterpret_cast<uint4*>(dst) = V.q;
    } else {            // encoder weights, hi/lo split
        const float* src = nullptr; int K, N, nt, s, stacked = 0;
        ushort_t *dh, *dl;
        if (blk < 513)      { int i = blk - 209; nt = i / 16; s = i % 16; src = qw1; K = 512; N = 300;
                              dh = w1hi + ((nt * 16 + s) * 64 + l) * 8; dl = w1lo + ((nt * 16 + s) * 64 + l) * 8; }
        else if (blk < 703) { int i = blk - 513; nt = i / 10; s = i % 10; src = qw2; K = 300; N = 300;
                              dh = w2hi + ((nt * 10 + s) * 64 + l) * 8; dl = w2lo + ((nt * 10 + s) * 64 + l) * 8; }
        else                { int i = blk - 703; nt = i / 10; s = i % 10; K = 300; N = 64; stacked = 1;
                              dh = w3hi + ((nt * 10 + s) * 64 + l) * 8; dl = w3lo + ((nt * 10 + s) * 64 + l) * 8; }
        int n = nt * 16 + li;
        B8 Vh, Vl;
        #pragma unroll
        for (int i = 0; i < 8; ++i) {
            int k = 32 * s + 8 * grp + i;
            float v = 0.f;
            if (k < K && n < N) {
                if (!stacked) v = src[k * N + n];
                else          v = (n < 32) ? zmw[k * 32 + n] : zlw[k * 32 + (n - 32)];
            }
            ushort_t h = f2bf(v);
            Vh.u[i] = h;
            Vl.u[i] = f2bf(v - bf2f(h));
        }
        *reinterpret_cast<uint4*>(dh) = Vh.q;
        *reinterpret_cast<uint4*>(dl) = Vl.q;
    }
}

// ------------- encoder GEMM, split-bf16 (~fp32 accuracy): out = act(A @ W + bias) -------
// block = 16 rows, 4 waves split NTILES n-tiles; A fp32 row-major, lda = row stride
template<int KSTEPS, int NTILES, bool RELU>
__global__ __launch_bounds__(256) void enc_gemm_f32(const float* __restrict__ A, int lda,
        const ushort_t* __restrict__ Whi, const ushort_t* __restrict__ Wlo,
        const float* __restrict__ bias, float* __restrict__ out, int ldo, int Ncols) {
    const int tid = threadIdx.x;
    const int w = tid >> 6, lane = tid & 63;
    const int grp = lane >> 4, li = lane & 15;
    const int r0 = blockIdx.x * 16;
    constexpr int NTL = (NTILES + 3) / 4;
    const int nbeg = w * NTL;
    int nl = NTILES - nbeg; if (nl < 0) nl = 0; if (nl > NTL) nl = NTL;
    const int nlocal = nl;

    f32x4 acc[NTL];
    #pragma unroll
    for (int i = 0; i < NTL; ++i) acc[i] = {0.f, 0.f, 0.f, 0.f};

    for (int s = 0; s < KSTEPS; ++s) {
        int kb = 32 * s + 8 * grp;
        B8 Ah, Al;
        if (kb < lda) {
            const float* ap = A + (size_t)(r0 + li) * lda + kb;
            float4 f0 = *reinterpret_cast<const float4*>(ap);
            float4 f1 = *reinterpret_cast<const float4*>(ap + 4);
            float fv[8] = {f0.x, f0.y, f0.z, f0.w, f1.x, f1.y, f1.z, f1.w};
            #pragma unroll
            for (int i = 0; i < 8; ++i) {
                ushort_t h = f2bf(fv[i]);
                Ah.u[i] = h;
                Al.u[i] = f2bf(fv[i] - bf2f(h));
            }
        } else {
            Ah.q = make_uint4(0, 0, 0, 0);
            Al.q = make_uint4(0, 0, 0, 0);
        }
        #pragma unroll
        for (int ntl = 0; ntl < NTL; ++ntl) {
            if (ntl < nlocal) {
                int nt = nbeg + ntl;
                bf16x8 bh = *reinterpret_cast<const bf16x8*>(
                    Whi + ((size_t)(nt * KSTEPS + s) * 64 + lane) * 8);
                bf16x8 bl = *reinterpret_cast<const bf16x8*>(
                    Wlo + ((size_t)(nt * KSTEPS + s) * 64 + lane) * 8);
                acc[ntl] = __builtin_amdgcn_mfma_f32_16x16x32_bf16(Ah.v, bh, acc[ntl], 0, 0, 0);
                acc[ntl] = __builtin_amdgcn_mfma_f32_16x16x32_bf16(Al.v, bh, acc[ntl], 0, 0, 0);
                acc[ntl] = __builtin_amdgcn_mfma_f32_16x16x32_bf16(Ah.v, bl, acc[ntl], 0, 0, 0);
            }
        }
    }
    #pragma unroll
    for (int ntl = 0; ntl < NTL; ++ntl) {
        if (ntl < nlocal) {
            int h = (nbeg + ntl) * 16 + li;
            float bv = (bias != nullptr && h < Ncols) ? bias[h] : 0.f;
            #pragma unroll
            for (int r = 0; r < 4; ++r) {
                float v = acc[ntl][r] + bv;
                if (RELU) v = fmaxf(v, 0.f);
                if (h >= Ncols) v = 0.f;
                out[(size_t)(r0 + 4 * grp + r) * ldo + h] = v;
            }
        }
    }
}

// -------- latent head (split-bf16) + reparameterize, fused: zm|zl = h2 @ w3; z = ... -----
__global__ __launch_bounds__(256) void enc3_reparam(const float* __restrict__ h2,
        const ushort_t* __restrict__ w3hi, const ushort_t* __restrict__ w3lo,
        const float* __restrict__ zmb, const float* __restrict__ zlb,
        const float* __restrict__ eps, float* __restrict__ out, float* __restrict__ zb) {
    __shared__ float zs[16][64];
    const int tid = threadIdx.x;
    const int w = tid >> 6, lane = tid & 63;
    const int grp = lane >> 4, li = lane & 15;
    const int r0 = blockIdx.x * 16;

    f32x4 acc = {0.f, 0.f, 0.f, 0.f};
    for (int s = 0; s < 10; ++s) {
        int kb = 32 * s + 8 * grp;
        B8 Ah, Al;
        if (kb < 304) {
            const float* ap = h2 + (size_t)(r0 + li) * 304 + kb;
            float4 f0 = *reinterpret_cast<const float4*>(ap);
            float4 f1 = *reinterpret_cast<const float4*>(ap + 4);
            float fv[8] = {f0.x, f0.y, f0.z, f0.w, f1.x, f1.y, f1.z, f1.w};
            #pragma unroll
            for (int i = 0; i < 8; ++i) {
                ushort_t h = f2bf(fv[i]);
                Ah.u[i] = h;
                Al.u[i] = f2bf(fv[i] - bf2f(h));
            }
        } else {
            Ah.q = make_uint4(0, 0, 0, 0);
            Al.q = make_uint4(0, 0, 0, 0);
        }
        bf16x8 bh = *reinterpret_cast<const bf16x8*>(w3hi + ((size_t)(w * 10 + s) * 64 + lane) * 8);
        bf16x8 bl = *reinterpret_cast<const bf16x8*>(w3lo + ((size_t)(w * 10 + s) * 64 + lane) * 8);
        acc = __builtin_amdgcn_mfma_f32_16x16x32_bf16(Ah.v, bh, acc, 0, 0, 0);
        acc = __builtin_amdgcn_mfma_f32_16x16x32_bf16(Al.v, bh, acc, 0, 0, 0);
        acc = __builtin_amdgcn_mfma_f32_16x16x32_bf16(Ah.v, bl, acc, 0, 0, 0);
    }
    #pragma unroll
    for (int r = 0; r < 4; ++r) zs[4 * grp + r][w * 16 + li] = acc[r];
    __syncthreads();

    for (int idx = tid; idx < 512; idx += 256) {
        int m = idx >> 5, l2 = idx & 31;
        int row = r0 + m;
        float zm = zs[m][l2] + zmb[l2];
        float zl = zs[m][32 + l2] + zlb[l2];
        float zv = zm + eps[row * 32 + l2] * expf(0.5f * zl);
        out[B_ * D_ + row * 32 + l2] = zv;
        out[B_ * D_ + B_ * L_ + row * 32 + l2] = zm;
        out[B_ * D_ + 2 * B_ * L_ + row * 32 + l2] = zl;
        zb[row * 32 + l2] = zv;
    }
}

// ---------------- decoder: one block = (column j, 64 batch rows), MFMA ----------------
__global__ __launch_bounds__(256, 3) void decode_kernel(
        const float* __restrict__ z, const float* __restrict__ Wmask,
        const ushort_t* __restrict__ gw1f, const ushort_t* __restrict__ gw2f,
        const float* __restrict__ gb2, const float* __restrict__ colw,
        const float* __restrict__ colb, float* __restrict__ xmean) {
    __shared__ __align__(16) ushort_t mf[4 * 64 * 8];        // masked B-fragments (bf16)
    __shared__ __align__(16) ushort_t g1s[64 * G1S + 16];    // g1 bf16 [64][G1S] + tail pad
    __shared__ float xrec[64];

    const int j    = blockIdx.y;
    const int b0   = blockIdx.x * 64;
    const int tid  = threadIdx.x;
    const int w    = tid >> 6;
    const int lane = tid & 63;
    const int grp  = lane >> 4, li = lane & 15;

    // phase 0: build masked B-frags (masked^T: B[k][b] = W[j][k]*z[b][k])
    {
        int b = b0 + w * 16 + li;
        const float* zp = z + (size_t)b * L_ + 8 * grp;
        const float* wp = Wmask + (size_t)j * L_ + 8 * grp;
        float4 z0 = *reinterpret_cast<const float4*>(zp);
        float4 z1 = *reinterpret_cast<const float4*>(zp + 4);
        float4 w0 = *reinterpret_cast<const float4*>(wp);
        float4 w1 = *reinterpret_cast<const float4*>(wp + 4);
        B8 V;
        V.u[0] = f2bf(w0.x * z0.x); V.u[1] = f2bf(w0.y * z0.y);
        V.u[2] = f2bf(w0.z * z0.z); V.u[3] = f2bf(w0.w * z0.w);
        V.u[4] = f2bf(w1.x * z1.x); V.u[5] = f2bf(w1.y * z1.y);
        V.u[6] = f2bf(w1.z * z1.z); V.u[7] = f2bf(w1.w * z1.w);
        *reinterpret_cast<uint4*>(&mf[(w * 64 + lane) * 8]) = V.q;
        if (tid < 64) xrec[tid] = 0.f;
        // zero pad cols [304,312) all rows + 16-elem tail (phase-2 reads touch them)
        for (int idx = tid; idx < 64 * 8 + 16; idx += 256) {
            int r = idx >> 3, c = 304 + (idx & 7);
            g1s[(idx < 512) ? (r * G1S + c) : (64 * G1S + (idx - 512))] = 0;
        }
    }
    __syncthreads();

    const int nlocal = (w == 3) ? 4 : 5;          // n-tiles 19 = 5+5+5+4 across waves

    // phase 1 (operand-swapped): D = gw1^T @ masked^T = g1^T; lane holds 4 consecutive h
    {
        bf16x8 bm[4];
        #pragma unroll
        for (int mt = 0; mt < 4; ++mt)
            bm[mt] = *reinterpret_cast<const bf16x8*>(&mf[(mt * 64 + lane) * 8]);
        #pragma unroll
        for (int ntl = 0; ntl < 5; ++ntl) {
            if (ntl < nlocal) {
                int nt = w * 5 + ntl;
                bf16x8 ga = *reinterpret_cast<const bf16x8*>(gw1f + (nt * 64 + lane) * 8);
                #pragma unroll
                for (int mt = 0; mt < 4; ++mt) {
                    f32x4 c = {0.f, 0.f, 0.f, 0.f};
                    c = __builtin_amdgcn_mfma_f32_16x16x32_bf16(ga, bm[mt], c, 0, 0, 0);
                    // c[r] = g1[b = mt*16+li][h = nt*16 + 4*grp + r]
                    uint2 p;
                    p.x = pack2(fmaxf(c[0], 0.f), fmaxf(c[1], 0.f));
                    p.y = pack2(fmaxf(c[2], 0.f), fmaxf(c[3], 0.f));
                    *reinterpret_cast<uint2*>(&g1s[(mt * 16 + li) * G1S + nt * 16 + 4 * grp]) = p;
                }
            }
        }
    }
    __syncthreads();

    // phase 2: g2 = relu(g1 @ gw2 + gb2) with B-frag prefetch; fused colw-dot epilogue
    {
        f32x4 acc[4][5];
        #pragma unroll
        for (int mt = 0; mt < 4; ++mt)
            #pragma unroll
            for (int n = 0; n < 5; ++n) acc[mt][n] = {0.f, 0.f, 0.f, 0.f};

        bf16x8 bcur[5], bnext[5];
        #pragma unroll
        for (int ntl = 0; ntl < 5; ++ntl)
            if (ntl < nlocal)
                bcur[ntl] = *reinterpret_cast<const bf16x8*>(
                    gw2f + ((size_t)((w * 5 + ntl) * NS) * 64 + lane) * 8);

        for (int s = 0; s < NS; ++s) {
            bf16x8 af[4];
            #pragma unroll
            for (int mt = 0; mt < 4; ++mt)
                af[mt] = *reinterpret_cast<const bf16x8*>(
                    &g1s[(mt * 16 + li) * G1S + 32 * s + 8 * grp]);
            if (s + 1 < NS) {
                #pragma unroll
                for (int ntl = 0; ntl < 5; ++ntl)
                    if (ntl < nlocal)
                        bnext[ntl] = *reinterpret_cast<const bf16x8*>(
                            gw2f + ((size_t)((w * 5 + ntl) * NS + s + 1) * 64 + lane) * 8);
            }
            #pragma unroll
            for (int ntl = 0; ntl < 5; ++ntl) {
                if (ntl < nlocal) {
                    #pragma unroll
                    for (int mt = 0; mt < 4; ++mt)
                        acc[mt][ntl] = __builtin_amdgcn_mfma_f32_16x16x32_bf16(
                            af[mt], bcur[ntl], acc[mt][ntl], 0, 0, 0);
                }
            }
            #pragma unroll
            for (int ntl = 0; ntl < 5; ++ntl) bcur[ntl] = bnext[ntl];
        }

        // epilogue: relu(acc + gb2) * colw[j], reduce over h
        float partial[4][4] = {};
        #pragma unroll
        for (int ntl = 0; ntl < 5; ++ntl) {
            if (ntl < nlocal) {
                int h = (w * 5 + ntl) * 16 + li;
                float bias = 0.f, fac = 0.f;
                if (h < H_) { bias = gb2[h]; fac = colw[j * H_ + h]; }
                #pragma unroll
                for (int mt = 0; mt < 4; ++mt)
                    #pragma unroll
                    for (int r = 0; r < 4; ++r)
                        partial[mt][r] += fmaxf(acc[mt][ntl][r] + bias, 0.f) * fac;
            }
        }
        #pragma unroll
        for (int mt = 0; mt < 4; ++mt)
            #pragma unroll
            for (int r = 0; r < 4; ++r) {
                float v = partial[mt][r];
                v += __shfl_xor(v, 1);
                v += __shfl_xor(v, 2);
                v += __shfl_xor(v, 4);
                v += __shfl_xor(v, 8);
                if (li == 0) atomicAdd(&xrec[mt * 16 + grp * 4 + r], v);
            }
    }
    __syncthreads();

    if (tid < 64) xmean[(size_t)(b0 + tid) * D_ + j] = xrec[tid] + colb[j];
}

extern "C" void kernel_launch(void* const* d_in, const int* in_sizes, int n_in,
                              void* d_out, int out_size, void* d_ws, size_t ws_size,
                              hipStream_t stream) {
    const float* x     = (const float*)d_in[0];
    const float* eps   = (const float*)d_in[1];
    const float* Wm    = (const float*)d_in[2];
    const float* qz_w1 = (const float*)d_in[3];
    const float* qz_b1 = (const float*)d_in[4];
    const float* qz_w2 = (const float*)d_in[5];
    const float* qz_b2 = (const float*)d_in[6];
    const float* zm_w  = (const float*)d_in[7];
    const float* zm_b  = (const float*)d_in[8];
    const float* zl_w  = (const float*)d_in[9];
    const float* zl_b  = (const float*)d_in[10];
    const float* gw1   = (const float*)d_in[11];
    const float* gw2   = (const float*)d_in[12];
    const float* gb2   = (const float*)d_in[13];
    const float* colw  = (const float*)d_in[14];
    const float* colb  = (const float*)d_in[15];
    float* out = (float*)d_out;
    char* ws = (char*)d_ws;

    // workspace layout (bytes)
    ushort_t* gw1f = (ushort_t*)(ws + 0);          //  19,456 B
    ushort_t* gw2f = (ushort_t*)(ws + 19456);      // 194,560 B -> 214,016
    ushort_t* w1hi = (ushort_t*)(ws + 214016);     // 311,296 B -> 525,312
    ushort_t* w1lo = (ushort_t*)(ws + 525312);     // 311,296 B -> 836,608
    ushort_t* w2hi = (ushort_t*)(ws + 836608);     // 194,560 B -> 1,031,168
    ushort_t* w2lo = (ushort_t*)(ws + 1031168);    // 194,560 B -> 1,225,728
    ushort_t* w3hi = (ushort_t*)(ws + 1225728);    //  40,960 B -> 1,266,688
    ushort_t* w3lo = (ushort_t*)(ws + 1266688);    //  40,960 B -> 1,307,648
    float*    h1   = (float*)(ws + 1307648);       // 622,592 B -> 1,930,240  [512][304] f32
    float*    h2   = (float*)(ws + 214016);        // 622,592 B (overlaps dead w1hi/w1lo)
    float*    zb   = (float*)(ws + 1930240);       //  65,536 B -> 1,995,776  [512][32] f32

    prep_kernel<<<743, 64, 0, stream>>>(gw1, gw2, qz_w1, qz_w2, zm_w, zl_w,
                                        gw1f, gw2f, w1hi, w1lo, w2hi, w2lo, w3hi, w3lo);
    enc_gemm_f32<16, NT, true><<<32, 256, 0, stream>>>(x, 512, w1hi, w1lo, qz_b1, h1, 304, 300);
    enc_gemm_f32<10, NT, true><<<32, 256, 0, stream>>>(h1, 304, w2hi, w2lo, qz_b2, h2, 304, 300);
    enc3_reparam<<<32, 256, 0, stream>>>(h2, w3hi, w3lo, zm_b, zl_b, eps, out, zb);
    decode_kernel<<<dim3(8, 512), 256, 0, stream>>>(zb, Wm, gw1f, gw2f, gb2, colw, colb, out);
}

// Round 5
// 136.604 us; speedup vs baseline: 1.9422x; 1.9422x over previous
//
#include <hip/hip_runtime.h>

#define B_ 512
#define D_ 512
#define L_ 32
#define H_ 300
#define NT 19       // 16-col n-tiles of H
#define NS 10       // 32-k steps over K=300 (zero-padded weights beyond 300)
#define G1S 308     // g1 LDS row stride (ushorts): conflict-free stores, 2-way reads

typedef unsigned short ushort_t;
typedef __bf16 bf16x8 __attribute__((ext_vector_type(8)));
typedef float f32x4 __attribute__((ext_vector_type(4)));

__device__ __forceinline__ float bf2f(unsigned int hi16) {
    return __uint_as_float(hi16 << 16);
}
__device__ __forceinline__ ushort_t f2bf(float f) {
    unsigned int u = __float_as_uint(f);
    u += 0x7fffu + ((u >> 16) & 1u);   // RNE (finite inputs)
    return (ushort_t)(u >> 16);
}

union B8 { ushort_t u[8]; uint4 q; bf16x8 v; uint2 d[2]; };

// ---------------- prep: swizzle weights into MFMA B-fragment layout ----------------
// frag elem i of lane l = B[k = 32*s + 8*(l>>4) + i][n = 16*nt + (l&15)]; OOR -> 0
// decoder weights: single bf16; encoder weights: hi/lo bf16 pair (split-fp32)
__global__ __launch_bounds__(64) void prep_kernel(
        const float* __restrict__ gw1, const float* __restrict__ gw2,
        const float* __restrict__ qw1, const float* __restrict__ qw2,
        const float* __restrict__ zmw, const float* __restrict__ zlw,
        ushort_t* __restrict__ gw1f, ushort_t* __restrict__ gw2f,
        ushort_t* __restrict__ w1hi, ushort_t* __restrict__ w1lo,
        ushort_t* __restrict__ w2hi, ushort_t* __restrict__ w2lo,
        ushort_t* __restrict__ w3hi, ushort_t* __restrict__ w3lo) {
    int blk = blockIdx.x;
    int l = threadIdx.x, grp = l >> 4, li = l & 15;
    if (blk < 209) {    // decoder weights, single bf16
        const float* src; int K, nt, s; ushort_t* dst;
        if (blk < 19) { nt = blk; s = 0; src = gw1; K = 32; dst = gw1f + (nt * 64 + l) * 8; }
        else { int i = blk - 19; nt = i / 10; s = i % 10; src = gw2; K = 300;
               dst = gw2f + ((nt * 10 + s) * 64 + l) * 8; }
        int n = nt * 16 + li;
        B8 V;
        #pragma unroll
        for (int i = 0; i < 8; ++i) {
            int k = 32 * s + 8 * grp + i;
            V.u[i] = f2bf((k < K && n < H_) ? src[k * H_ + n] : 0.f);
        }
        *reinterpret_cast<uint4*>(dst) = V.q;
    } else {            // encoder weights, hi/lo split
        const float* src = nullptr; int K, N, nt, s, stacked = 0;
        ushort_t *dh, *dl;
        if (blk < 513)      { int i = blk - 209; nt = i / 16; s = i % 16; src = qw1; K = 512; N = 300;
                              dh = w1hi + ((nt * 16 + s) * 64 + l) * 8; dl = w1lo + ((nt * 16 + s) * 64 + l) * 8; }
        else if (blk < 703) { int i = blk - 513; nt = i / 10; s = i % 10; src = qw2; K = 300; N = 300;
                              dh = w2hi + ((nt * 10 + s) * 64 + l) * 8; dl = w2lo + ((nt * 10 + s) * 64 + l) * 8; }
        else                { int i = blk - 703; nt = i / 10; s = i % 10; K = 300; N = 64; stacked = 1;
                              dh = w3hi + ((nt * 10 + s) * 64 + l) * 8; dl = w3lo + ((nt * 10 + s) * 64 + l) * 8; }
        int n = nt * 16 + li;
        B8 Vh, Vl;
        #pragma unroll
        for (int i = 0; i < 8; ++i) {
            int k = 32 * s + 8 * grp + i;
            float v = 0.f;
            if (k < K && n < N) {
                if (!stacked) v = src[k * N + n];
                else          v = (n < 32) ? zmw[k * 32 + n] : zlw[k * 32 + (n - 32)];
            }
            ushort_t h = f2bf(v);
            Vh.u[i] = h;
            Vl.u[i] = f2bf(v - bf2f(h));
        }
        *reinterpret_cast<uint4*>(dh) = Vh.q;
        *reinterpret_cast<uint4*>(dl) = Vl.q;
    }
}

// ------------- encoder GEMM, split-bf16 (~fp32 accuracy): out = act(A @ W + bias) -------
// grid (M/16, ceil(N/64)); block = 16 rows, wave w owns n-tile blockIdx.y*4 + w
template<int KSTEPS, bool RELU>
__global__ __launch_bounds__(256) void enc_gemm_f32(const float* __restrict__ A, int lda,
        const ushort_t* __restrict__ Whi, const ushort_t* __restrict__ Wlo,
        const float* __restrict__ bias, float* __restrict__ out, int ldo,
        int Ncols, int ntiles) {
    const int tid = threadIdx.x;
    const int w = tid >> 6, lane = tid & 63;
    const int grp = lane >> 4, li = lane & 15;
    const int r0 = blockIdx.x * 16;
    const int nt = blockIdx.y * 4 + w;
    const bool active = nt < ntiles;

    f32x4 acc = {0.f, 0.f, 0.f, 0.f};
    for (int s = 0; s < KSTEPS; ++s) {
        int kb = 32 * s + 8 * grp;
        B8 Ah, Al;
        if (kb + 8 <= lda) {
            const float* ap = A + (size_t)(r0 + li) * lda + kb;
            float4 f0 = *reinterpret_cast<const float4*>(ap);
            float4 f1 = *reinterpret_cast<const float4*>(ap + 4);
            float fv[8] = {f0.x, f0.y, f0.z, f0.w, f1.x, f1.y, f1.z, f1.w};
            #pragma unroll
            for (int i = 0; i < 8; ++i) {
                ushort_t h = f2bf(fv[i]);
                Ah.u[i] = h;
                Al.u[i] = f2bf(fv[i] - bf2f(h));
            }
        } else {
            Ah.q = make_uint4(0, 0, 0, 0);
            Al.q = make_uint4(0, 0, 0, 0);
        }
        if (active) {
            bf16x8 bh = *reinterpret_cast<const bf16x8*>(
                Whi + ((size_t)(nt * KSTEPS + s) * 64 + lane) * 8);
            bf16x8 bl = *reinterpret_cast<const bf16x8*>(
                Wlo + ((size_t)(nt * KSTEPS + s) * 64 + lane) * 8);
            acc = __builtin_amdgcn_mfma_f32_16x16x32_bf16(Ah.v, bh, acc, 0, 0, 0);
            acc = __builtin_amdgcn_mfma_f32_16x16x32_bf16(Al.v, bh, acc, 0, 0, 0);
            acc = __builtin_amdgcn_mfma_f32_16x16x32_bf16(Ah.v, bl, acc, 0, 0, 0);
        }
    }
    if (active) {
        int h = nt * 16 + li;
        float bv = (bias != nullptr && h < Ncols) ? bias[h] : 0.f;
        #pragma unroll
        for (int r = 0; r < 4; ++r) {
            float v = acc[r] + bv;
            if (RELU) v = fmaxf(v, 0.f);
            if (h >= Ncols) v = 0.f;
            out[(size_t)(r0 + 4 * grp + r) * ldo + h] = v;
        }
    }
}

// -------- latent head (split-bf16) + reparameterize, fused: zm|zl = h2 @ w3; z = ... -----
__global__ __launch_bounds__(256) void enc3_reparam(const float* __restrict__ h2,
        const ushort_t* __restrict__ w3hi, const ushort_t* __restrict__ w3lo,
        const float* __restrict__ zmb, const float* __restrict__ zlb,
        const float* __restrict__ eps, float* __restrict__ out, float* __restrict__ zb) {
    __shared__ float zs[16][64];
    const int tid = threadIdx.x;
    const int w = tid >> 6, lane = tid & 63;
    const int grp = lane >> 4, li = lane & 15;
    const int r0 = blockIdx.x * 16;

    f32x4 acc = {0.f, 0.f, 0.f, 0.f};
    for (int s = 0; s < 10; ++s) {
        int kb = 32 * s + 8 * grp;
        B8 Ah, Al;
        if (kb + 8 <= 304) {
            const float* ap = h2 + (size_t)(r0 + li) * 304 + kb;
            float4 f0 = *reinterpret_cast<const float4*>(ap);
            float4 f1 = *reinterpret_cast<const float4*>(ap + 4);
            float fv[8] = {f0.x, f0.y, f0.z, f0.w, f1.x, f1.y, f1.z, f1.w};
            #pragma unroll
            for (int i = 0; i < 8; ++i) {
                ushort_t h = f2bf(fv[i]);
                Ah.u[i] = h;
                Al.u[i] = f2bf(fv[i] - bf2f(h));
            }
        } else {
            Ah.q = make_uint4(0, 0, 0, 0);
            Al.q = make_uint4(0, 0, 0, 0);
        }
        bf16x8 bh = *reinterpret_cast<const bf16x8*>(w3hi + ((size_t)(w * 10 + s) * 64 + lane) * 8);
        bf16x8 bl = *reinterpret_cast<const bf16x8*>(w3lo + ((size_t)(w * 10 + s) * 64 + lane) * 8);
        acc = __builtin_amdgcn_mfma_f32_16x16x32_bf16(Ah.v, bh, acc, 0, 0, 0);
        acc = __builtin_amdgcn_mfma_f32_16x16x32_bf16(Al.v, bh, acc, 0, 0, 0);
        acc = __builtin_amdgcn_mfma_f32_16x16x32_bf16(Ah.v, bl, acc, 0, 0, 0);
    }
    #pragma unroll
    for (int r = 0; r < 4; ++r) zs[4 * grp + r][w * 16 + li] = acc[r];
    __syncthreads();

    for (int idx = tid; idx < 512; idx += 256) {
        int m = idx >> 5, l2 = idx & 31;
        int row = r0 + m;
        float zm = zs[m][l2] + zmb[l2];
        float zl = zs[m][32 + l2] + zlb[l2];
        float zv = zm + eps[row * 32 + l2] * expf(0.5f * zl);
        out[B_ * D_ + row * 32 + l2] = zv;
        out[B_ * D_ + B_ * L_ + row * 32 + l2] = zm;
        out[B_ * D_ + 2 * B_ * L_ + row * 32 + l2] = zl;
        zb[row * 32 + l2] = zv;
    }
}

// ---------------- decoder: one block = (column j, 64 batch rows), 8 waves ----------------
// wave w owns n-tiles {w, w+8, w+16(if w<3)}; acc[4 m-tiles][<=3 n-tiles] = 48 VGPRs
__global__ __launch_bounds__(512, 4) void decode_kernel(
        const float* __restrict__ z, const float* __restrict__ Wmask,
        const ushort_t* __restrict__ gw1f, const ushort_t* __restrict__ gw2f,
        const float* __restrict__ gb2, const float* __restrict__ colw,
        const float* __restrict__ colb, float* __restrict__ xmean) {
    __shared__ __align__(16) ushort_t g1s[64 * G1S + 16];    // 39,456 B
    __shared__ float xrec[64];

    const int j    = blockIdx.y;
    const int b0   = blockIdx.x * 64;
    const int tid  = threadIdx.x;
    const int w    = tid >> 6;
    const int lane = tid & 63;
    const int grp  = lane >> 4, li = lane & 15;
    const int ntl  = (w < 3) ? 3 : 2;             // n-tiles this wave: w, w+8, (w+16)

    // phase 0: masked A-frags in registers (all 4 m-tiles, per wave); zero pads
    B8 bm[4];
    {
        const float* wp = Wmask + (size_t)j * L_ + 8 * grp;
        float4 w0 = *reinterpret_cast<const float4*>(wp);
        float4 w1 = *reinterpret_cast<const float4*>(wp + 4);
        #pragma unroll
        for (int mt = 0; mt < 4; ++mt) {
            const float* zp = z + (size_t)(b0 + mt * 16 + li) * L_ + 8 * grp;
            float4 z0 = *reinterpret_cast<const float4*>(zp);
            float4 z1 = *reinterpret_cast<const float4*>(zp + 4);
            bm[mt].u[0] = f2bf(w0.x * z0.x); bm[mt].u[1] = f2bf(w0.y * z0.y);
            bm[mt].u[2] = f2bf(w0.z * z0.z); bm[mt].u[3] = f2bf(w0.w * z0.w);
            bm[mt].u[4] = f2bf(w1.x * z1.x); bm[mt].u[5] = f2bf(w1.y * z1.y);
            bm[mt].u[6] = f2bf(w1.z * z1.z); bm[mt].u[7] = f2bf(w1.w * z1.w);
        }
        if (tid < 64) xrec[tid] = 0.f;
        // zero A-pad cols 304..307 (never written by phase 1) + 16-elem tail:
        // phase-2 s=9 reads cols up to 319 -> spill into next row (finite g1) or tail
        if (tid < 272) {
            if (tid < 256) g1s[(tid >> 2) * G1S + 304 + (tid & 3)] = 0;
            else           g1s[64 * G1S + (tid - 256)] = 0;
        }
    }
    __syncthreads();

    // phase 1: g1 = relu(masked @ gw1) [K=32, one MFMA step per (mt, nt)]
    #pragma unroll
    for (int t = 0; t < 3; ++t) {
        if (t < ntl) {
            int nt = w + 8 * t;
            bf16x8 ga = *reinterpret_cast<const bf16x8*>(gw1f + (nt * 64 + lane) * 8);
            #pragma unroll
            for (int mt = 0; mt < 4; ++mt) {
                f32x4 c = {0.f, 0.f, 0.f, 0.f};
                c = __builtin_amdgcn_mfma_f32_16x16x32_bf16(bm[mt].v, ga, c, 0, 0, 0);
                // C/D: row = 4*grp + r (batch), col = li (h)
                #pragma unroll
                for (int r = 0; r < 4; ++r)
                    g1s[(mt * 16 + 4 * grp + r) * G1S + nt * 16 + li] =
                        f2bf(fmaxf(c[r], 0.f));
            }
        }
    }
    __syncthreads();

    // phase 2: g2 = relu(g1 @ gw2 + gb2); fused colw-dot epilogue
    {
        f32x4 acc[4][3];
        #pragma unroll
        for (int mt = 0; mt < 4; ++mt)
            #pragma unroll
            for (int t = 0; t < 3; ++t) acc[mt][t] = {0.f, 0.f, 0.f, 0.f};

        for (int s = 0; s < NS; ++s) {
            B8 af[4];
            #pragma unroll
            for (int mt = 0; mt < 4; ++mt) {
                const ushort_t* p = &g1s[(mt * 16 + li) * G1S + 32 * s + 8 * grp];
                af[mt].d[0] = *reinterpret_cast<const uint2*>(p);
                af[mt].d[1] = *reinterpret_cast<const uint2*>(p + 4);
            }
            #pragma unroll
            for (int t = 0; t < 3; ++t) {
                if (t < ntl) {
                    int nt = w + 8 * t;
                    bf16x8 bfr = *reinterpret_cast<const bf16x8*>(
                        gw2f + ((size_t)(nt * NS + s) * 64 + lane) * 8);
                    #pragma unroll
                    for (int mt = 0; mt < 4; ++mt)
                        acc[mt][t] = __builtin_amdgcn_mfma_f32_16x16x32_bf16(
                            af[mt].v, bfr, acc[mt][t], 0, 0, 0);
                }
            }
        }

        // epilogue: relu(acc + gb2) * colw[j], reduce over h
        float partial[4][4] = {};
        #pragma unroll
        for (int t = 0; t < 3; ++t) {
            if (t < ntl) {
                int h = (w + 8 * t) * 16 + li;
                float bias = 0.f, fac = 0.f;
                if (h < H_) { bias = gb2[h]; fac = colw[j * H_ + h]; }
                #pragma unroll
                for (int mt = 0; mt < 4; ++mt)
                    #pragma unroll
                    for (int r = 0; r < 4; ++r)
                        partial[mt][r] += fmaxf(acc[mt][t][r] + bias, 0.f) * fac;
            }
        }
        #pragma unroll
        for (int mt = 0; mt < 4; ++mt)
            #pragma unroll
            for (int r = 0; r < 4; ++r) {
                float v = partial[mt][r];
                v += __shfl_xor(v, 1);
                v += __shfl_xor(v, 2);
                v += __shfl_xor(v, 4);
                v += __shfl_xor(v, 8);
                if (li == 0) atomicAdd(&xrec[mt * 16 + grp * 4 + r], v);
            }
    }
    __syncthreads();

    if (tid < 64) xmean[(size_t)(b0 + tid) * D_ + j] = xrec[tid] + colb[j];
}

extern "C" void kernel_launch(void* const* d_in, const int* in_sizes, int n_in,
                              void* d_out, int out_size, void* d_ws, size_t ws_size,
                              hipStream_t stream) {
    const float* x     = (const float*)d_in[0];
    const float* eps   = (const float*)d_in[1];
    const float* Wm    = (const float*)d_in[2];
    const float* qz_w1 = (const float*)d_in[3];
    const float* qz_b1 = (const float*)d_in[4];
    const float* qz_w2 = (const float*)d_in[5];
    const float* qz_b2 = (const float*)d_in[6];
    const float* zm_w  = (const float*)d_in[7];
    const float* zm_b  = (const float*)d_in[8];
    const float* zl_w  = (const float*)d_in[9];
    const float* zl_b  = (const float*)d_in[10];
    const float* gw1   = (const float*)d_in[11];
    const float* gw2   = (const float*)d_in[12];
    const float* gb2   = (const float*)d_in[13];
    const float* colw  = (const float*)d_in[14];
    const float* colb  = (const float*)d_in[15];
    float* out = (float*)d_out;
    char* ws = (char*)d_ws;

    // workspace layout (bytes)
    ushort_t* gw1f = (ushort_t*)(ws + 0);          //  19,456 B
    ushort_t* gw2f = (ushort_t*)(ws + 19456);      // 194,560 B -> 214,016
    ushort_t* w1hi = (ushort_t*)(ws + 214016);     // 311,296 B -> 525,312
    ushort_t* w1lo = (ushort_t*)(ws + 525312);     // 311,296 B -> 836,608
    ushort_t* w2hi = (ushort_t*)(ws + 836608);     // 194,560 B -> 1,031,168
    ushort_t* w2lo = (ushort_t*)(ws + 1031168);    // 194,560 B -> 1,225,728
    ushort_t* w3hi = (ushort_t*)(ws + 1225728);    //  40,960 B -> 1,266,688
    ushort_t* w3lo = (ushort_t*)(ws + 1266688);    //  40,960 B -> 1,307,648
    float*    h1   = (float*)(ws + 1307648);       // 622,592 B -> 1,930,240  [512][304] f32
    float*    h2   = (float*)(ws + 214016);        // 622,592 B (overlaps dead w1hi/w1lo)
    float*    zb   = (float*)(ws + 1930240);       //  65,536 B -> 1,995,776  [512][32] f32

    prep_kernel<<<743, 64, 0, stream>>>(gw1, gw2, qz_w1, qz_w2, zm_w, zl_w,
                                        gw1f, gw2f, w1hi, w1lo, w2hi, w2lo, w3hi, w3lo);
    enc_gemm_f32<16, true><<<dim3(32, 5), 256, 0, stream>>>(
        x, 512, w1hi, w1lo, qz_b1, h1, 304, 300, NT);
    enc_gemm_f32<10, true><<<dim3(32, 5), 256, 0, stream>>>(
        h1, 304, w2hi, w2lo, qz_b2, h2, 304, 300, NT);
    enc3_reparam<<<32, 256, 0, stream>>>(h2, w3hi, w3lo, zm_b, zl_b, eps, out, zb);
    decode_kernel<<<dim3(8, 512), 512, 0, stream>>>(zb, Wm, gw1f, gw2f, gb2, colw, colb, out);
}

// Round 6
// 127.232 us; speedup vs baseline: 2.0852x; 1.0737x over previous
//
#include <hip/hip_runtime.h>

#define B_ 512
#define D_ 512
#define L_ 32
#define H_ 300
#define NT 19       // 16-col n-tiles of H
#define NS 10       // 32-k steps over K=300 (zero-padded weights beyond 300)
#define G1S 308     // g1 LDS row stride (ushorts): <=2-way on stores+reads (measured 0)

typedef unsigned short ushort_t;
typedef __bf16 bf16x8 __attribute__((ext_vector_type(8)));
typedef float f32x4 __attribute__((ext_vector_type(4)));

union B8 { ushort_t u[8]; uint4 q; bf16x8 v; uint2 d[2]; __bf16 b[8]; };

__device__ __forceinline__ void split8(const float* fv, B8& hi, B8& lo) {
    #pragma unroll
    for (int i = 0; i < 8; ++i) {
        __bf16 h = (__bf16)fv[i];
        hi.b[i] = h;
        lo.b[i] = (__bf16)(fv[i] - (float)h);
    }
}

// ---------------- prep: swizzle weights into MFMA B-fragment layout ----------------
// frag elem i of lane l = B[k = 32*s + 8*(l>>4) + i][n = 16*nt + (l&15)]; OOR -> 0
// decoder weights: single bf16; encoder weights: hi/lo bf16 pair (split-fp32)
__global__ __launch_bounds__(64) void prep_kernel(
        const float* __restrict__ gw1, const float* __restrict__ gw2,
        const float* __restrict__ qw1, const float* __restrict__ qw2,
        const float* __restrict__ zmw, const float* __restrict__ zlw,
        ushort_t* __restrict__ gw1f, ushort_t* __restrict__ gw2f,
        ushort_t* __restrict__ w1hi, ushort_t* __restrict__ w1lo,
        ushort_t* __restrict__ w2hi, ushort_t* __restrict__ w2lo,
        ushort_t* __restrict__ w3hi, ushort_t* __restrict__ w3lo) {
    int blk = blockIdx.x;
    int l = threadIdx.x, grp = l >> 4, li = l & 15;
    if (blk < 209) {    // decoder weights, single bf16
        const float* src; int K, nt, s; ushort_t* dst;
        if (blk < 19) { nt = blk; s = 0; src = gw1; K = 32; dst = gw1f + (nt * 64 + l) * 8; }
        else { int i = blk - 19; nt = i / 10; s = i % 10; src = gw2; K = 300;
               dst = gw2f + ((nt * 10 + s) * 64 + l) * 8; }
        int n = nt * 16 + li;
        B8 V;
        #pragma unroll
        for (int i = 0; i < 8; ++i) {
            int k = 32 * s + 8 * grp + i;
            V.b[i] = (__bf16)((k < K && n < H_) ? src[k * H_ + n] : 0.f);
        }
        *reinterpret_cast<uint4*>(dst) = V.q;
    } else {            // encoder weights, hi/lo split
        const float* src = nullptr; int K, N, nt, s, stacked = 0;
        ushort_t *dh, *dl;
        if (blk < 513)      { int i = blk - 209; nt = i / 16; s = i % 16; src = qw1; K = 512; N = 300;
                              dh = w1hi + ((nt * 16 + s) * 64 + l) * 8; dl = w1lo + ((nt * 16 + s) * 64 + l) * 8; }
        else if (blk < 703) { int i = blk - 513; nt = i / 10; s = i % 10; src = qw2; K = 300; N = 300;
                              dh = w2hi + ((nt * 10 + s) * 64 + l) * 8; dl = w2lo + ((nt * 10 + s) * 64 + l) * 8; }
        else                { int i = blk - 703; nt = i / 10; s = i % 10; K = 300; N = 64; stacked = 1;
                              dh = w3hi + ((nt * 10 + s) * 64 + l) * 8; dl = w3lo + ((nt * 10 + s) * 64 + l) * 8; }
        int n = nt * 16 + li;
        float fv[8];
        #pragma unroll
        for (int i = 0; i < 8; ++i) {
            int k = 32 * s + 8 * grp + i;
            float v = 0.f;
            if (k < K && n < N) {
                if (!stacked) v = src[k * N + n];
                else          v = (n < 32) ? zmw[k * 32 + n] : zlw[k * 32 + (n - 32)];
            }
            fv[i] = v;
        }
        B8 Vh, Vl;
        split8(fv, Vh, Vl);
        *reinterpret_cast<uint4*>(dh) = Vh.q;
        *reinterpret_cast<uint4*>(dl) = Vl.q;
    }
}

// ------------- encoder GEMM, split-bf16 (~fp32 accuracy): out = act(A @ W + bias) -------
// grid (M/16, ceil(N/64)); block = 16 rows, wave w owns n-tile blockIdx.y*4 + w
template<int KSTEPS, bool RELU>
__global__ __launch_bounds__(256) void enc_gemm_f32(const float* __restrict__ A, int lda,
        const ushort_t* __restrict__ Whi, const ushort_t* __restrict__ Wlo,
        const float* __restrict__ bias, float* __restrict__ out, int ldo,
        int Ncols, int ntiles) {
    const int tid = threadIdx.x;
    const int w = tid >> 6, lane = tid & 63;
    const int grp = lane >> 4, li = lane & 15;
    const int r0 = blockIdx.x * 16;
    const int nt = blockIdx.y * 4 + w;
    const bool active = nt < ntiles;

    f32x4 acc = {0.f, 0.f, 0.f, 0.f};
    for (int s = 0; s < KSTEPS; ++s) {
        int kb = 32 * s + 8 * grp;
        B8 Ah, Al;
        if (kb + 8 <= lda) {
            const float* ap = A + (size_t)(r0 + li) * lda + kb;
            float4 f0 = *reinterpret_cast<const float4*>(ap);
            float4 f1 = *reinterpret_cast<const float4*>(ap + 4);
            float fv[8] = {f0.x, f0.y, f0.z, f0.w, f1.x, f1.y, f1.z, f1.w};
            split8(fv, Ah, Al);
        } else {
            Ah.q = make_uint4(0, 0, 0, 0);
            Al.q = make_uint4(0, 0, 0, 0);
        }
        if (active) {
            bf16x8 bh = *reinterpret_cast<const bf16x8*>(
                Whi + ((size_t)(nt * KSTEPS + s) * 64 + lane) * 8);
            bf16x8 bl = *reinterpret_cast<const bf16x8*>(
                Wlo + ((size_t)(nt * KSTEPS + s) * 64 + lane) * 8);
            acc = __builtin_amdgcn_mfma_f32_16x16x32_bf16(Ah.v, bh, acc, 0, 0, 0);
            acc = __builtin_amdgcn_mfma_f32_16x16x32_bf16(Al.v, bh, acc, 0, 0, 0);
            acc = __builtin_amdgcn_mfma_f32_16x16x32_bf16(Ah.v, bl, acc, 0, 0, 0);
        }
    }
    if (active) {
        int h = nt * 16 + li;
        float bv = (bias != nullptr && h < Ncols) ? bias[h] : 0.f;
        #pragma unroll
        for (int r = 0; r < 4; ++r) {
            float v = acc[r] + bv;
            if (RELU) v = fmaxf(v, 0.f);
            if (h >= Ncols) v = 0.f;
            out[(size_t)(r0 + 4 * grp + r) * ldo + h] = v;
        }
    }
}

// -------- latent head (split-bf16) + reparameterize, fused: zm|zl = h2 @ w3; z = ... -----
__global__ __launch_bounds__(256) void enc3_reparam(const float* __restrict__ h2,
        const ushort_t* __restrict__ w3hi, const ushort_t* __restrict__ w3lo,
        const float* __restrict__ zmb, const float* __restrict__ zlb,
        const float* __restrict__ eps, float* __restrict__ out, float* __restrict__ zb) {
    __shared__ float zs[16][64];
    const int tid = threadIdx.x;
    const int w = tid >> 6, lane = tid & 63;
    const int grp = lane >> 4, li = lane & 15;
    const int r0 = blockIdx.x * 16;

    f32x4 acc = {0.f, 0.f, 0.f, 0.f};
    for (int s = 0; s < 10; ++s) {
        int kb = 32 * s + 8 * grp;
        B8 Ah, Al;
        if (kb + 8 <= 304) {
            const float* ap = h2 + (size_t)(r0 + li) * 304 + kb;
            float4 f0 = *reinterpret_cast<const float4*>(ap);
            float4 f1 = *reinterpret_cast<const float4*>(ap + 4);
            float fv[8] = {f0.x, f0.y, f0.z, f0.w, f1.x, f1.y, f1.z, f1.w};
            split8(fv, Ah, Al);
        } else {
            Ah.q = make_uint4(0, 0, 0, 0);
            Al.q = make_uint4(0, 0, 0, 0);
        }
        bf16x8 bh = *reinterpret_cast<const bf16x8*>(w3hi + ((size_t)(w * 10 + s) * 64 + lane) * 8);
        bf16x8 bl = *reinterpret_cast<const bf16x8*>(w3lo + ((size_t)(w * 10 + s) * 64 + lane) * 8);
        acc = __builtin_amdgcn_mfma_f32_16x16x32_bf16(Ah.v, bh, acc, 0, 0, 0);
        acc = __builtin_amdgcn_mfma_f32_16x16x32_bf16(Al.v, bh, acc, 0, 0, 0);
        acc = __builtin_amdgcn_mfma_f32_16x16x32_bf16(Ah.v, bl, acc, 0, 0, 0);
    }
    #pragma unroll
    for (int r = 0; r < 4; ++r) zs[4 * grp + r][w * 16 + li] = acc[r];
    __syncthreads();

    for (int idx = tid; idx < 512; idx += 256) {
        int m = idx >> 5, l2 = idx & 31;
        int row = r0 + m;
        float zm = zs[m][l2] + zmb[l2];
        float zl = zs[m][32 + l2] + zlb[l2];
        float zv = zm + eps[row * 32 + l2] * expf(0.5f * zl);
        out[B_ * D_ + row * 32 + l2] = zv;
        out[B_ * D_ + B_ * L_ + row * 32 + l2] = zm;
        out[B_ * D_ + 2 * B_ * L_ + row * 32 + l2] = zl;
        zb[row * 32 + l2] = zv;
    }
}

// ---------------- decoder: one block = (column j, 64 batch rows), 8 waves ----------------
// wave w owns n-tiles {w, w+8, w+16(if w<3)}; acc[4 m-tiles][<=3 n-tiles] = 48 AGPRs
__global__ __launch_bounds__(512, 4) void decode_kernel(
        const float* __restrict__ z, const float* __restrict__ Wmask,
        const ushort_t* __restrict__ gw1f, const ushort_t* __restrict__ gw2f,
        const float* __restrict__ gb2, const float* __restrict__ colw,
        const float* __restrict__ colb, float* __restrict__ xmean) {
    __shared__ __align__(16) ushort_t g1s[64 * G1S + 16];    // 39,456 B
    __shared__ float xpart[8][64];                           //  2,048 B

    const int j    = blockIdx.y;
    const int b0   = blockIdx.x * 64;
    const int tid  = threadIdx.x;
    const int w    = tid >> 6;
    const int lane = tid & 63;
    const int grp  = lane >> 4, li = lane & 15;
    const int ntl  = (w < 3) ? 3 : 2;             // n-tiles this wave: w, w+8, (w+16)

    // phase 0: masked B-frags in registers (all 4 m-tiles, per wave); zero pads
    B8 bm[4];
    {
        const float* wp = Wmask + (size_t)j * L_ + 8 * grp;
        float4 w0 = *reinterpret_cast<const float4*>(wp);
        float4 w1 = *reinterpret_cast<const float4*>(wp + 4);
        float wv[8] = {w0.x, w0.y, w0.z, w0.w, w1.x, w1.y, w1.z, w1.w};
        #pragma unroll
        for (int mt = 0; mt < 4; ++mt) {
            const float* zp = z + (size_t)(b0 + mt * 16 + li) * L_ + 8 * grp;
            float4 z0 = *reinterpret_cast<const float4*>(zp);
            float4 z1 = *reinterpret_cast<const float4*>(zp + 4);
            float zv[8] = {z0.x, z0.y, z0.z, z0.w, z1.x, z1.y, z1.z, z1.w};
            #pragma unroll
            for (int i = 0; i < 8; ++i) bm[mt].b[i] = (__bf16)(wv[i] * zv[i]);
        }
        // zero A-pad cols 304..307 (never written by phase 1) + 16-elem tail:
        // phase-2 s=9 reads cols up to 319 -> spill into next row (finite g1) or tail,
        // multiplied by zero-padded (k>=300) gw2f B entries
        if (tid < 272) {
            if (tid < 256) g1s[(tid >> 2) * G1S + 304 + (tid & 3)] = 0;
            else           g1s[64 * G1S + (tid - 256)] = 0;
        }
    }
    __syncthreads();

    // phase 1 (swapped): D = gw1^T(A) x masked^T(B) -> lane holds g1[b=li][4 consec h]
    #pragma unroll
    for (int t = 0; t < 3; ++t) {
        if (t < ntl) {
            int nt = w + 8 * t;
            bf16x8 ga = *reinterpret_cast<const bf16x8*>(gw1f + (nt * 64 + lane) * 8);
            #pragma unroll
            for (int mt = 0; mt < 4; ++mt) {
                f32x4 c = {0.f, 0.f, 0.f, 0.f};
                c = __builtin_amdgcn_mfma_f32_16x16x32_bf16(ga, bm[mt].v, c, 0, 0, 0);
                // c[r] = g1[b = mt*16+li][h = nt*16 + 4*grp + r]
                B8 P;
                #pragma unroll
                for (int r = 0; r < 4; ++r) P.b[r] = (__bf16)fmaxf(c[r], 0.f);
                *reinterpret_cast<uint2*>(&g1s[(mt * 16 + li) * G1S + nt * 16 + 4 * grp]) = P.d[0];
            }
        }
    }
    __syncthreads();

    // phase 2: g2 = relu(g1 @ gw2 + gb2); fused colw-dot epilogue
    {
        f32x4 acc[4][3];
        #pragma unroll
        for (int mt = 0; mt < 4; ++mt)
            #pragma unroll
            for (int t = 0; t < 3; ++t) acc[mt][t] = {0.f, 0.f, 0.f, 0.f};

        #pragma unroll 2
        for (int s = 0; s < NS; ++s) {
            B8 af[4];
            #pragma unroll
            for (int mt = 0; mt < 4; ++mt) {
                const ushort_t* p = &g1s[(mt * 16 + li) * G1S + 32 * s + 8 * grp];
                af[mt].d[0] = *reinterpret_cast<const uint2*>(p);
                af[mt].d[1] = *reinterpret_cast<const uint2*>(p + 4);
            }
            #pragma unroll
            for (int t = 0; t < 3; ++t) {
                if (t < ntl) {
                    int nt = w + 8 * t;
                    bf16x8 bfr = *reinterpret_cast<const bf16x8*>(
                        gw2f + ((size_t)(nt * NS + s) * 64 + lane) * 8);
                    #pragma unroll
                    for (int mt = 0; mt < 4; ++mt)
                        acc[mt][t] = __builtin_amdgcn_mfma_f32_16x16x32_bf16(
                            af[mt].v, bfr, acc[mt][t], 0, 0, 0);
                }
            }
        }

        // epilogue: relu(acc + gb2) * colw[j], reduce over h (li lanes), no atomics
        float partial[4][4] = {};
        #pragma unroll
        for (int t = 0; t < 3; ++t) {
            if (t < ntl) {
                int h = (w + 8 * t) * 16 + li;
                float bias = 0.f, fac = 0.f;
                if (h < H_) { bias = gb2[h]; fac = colw[j * H_ + h]; }
                #pragma unroll
                for (int mt = 0; mt < 4; ++mt)
                    #pragma unroll
                    for (int r = 0; r < 4; ++r)
                        partial[mt][r] += fmaxf(acc[mt][t][r] + bias, 0.f) * fac;
            }
        }
        #pragma unroll
        for (int mt = 0; mt < 4; ++mt)
            #pragma unroll
            for (int r = 0; r < 4; ++r) {
                float v = partial[mt][r];
                v += __shfl_xor(v, 1);
                v += __shfl_xor(v, 2);
                v += __shfl_xor(v, 4);
                v += __shfl_xor(v, 8);
                if (li == 0) xpart[w][mt * 16 + 4 * grp + r] = v;
            }
    }
    __syncthreads();

    if (tid < 64) {
        float v = colb[j];
        #pragma unroll
        for (int ww = 0; ww < 8; ++ww) v += xpart[ww][tid];
        xmean[(size_t)(b0 + tid) * D_ + j] = v;
    }
}

extern "C" void kernel_launch(void* const* d_in, const int* in_sizes, int n_in,
                              void* d_out, int out_size, void* d_ws, size_t ws_size,
                              hipStream_t stream) {
    const float* x     = (const float*)d_in[0];
    const float* eps   = (const float*)d_in[1];
    const float* Wm    = (const float*)d_in[2];
    const float* qz_w1 = (const float*)d_in[3];
    const float* qz_b1 = (const float*)d_in[4];
    const float* qz_w2 = (const float*)d_in[5];
    const float* qz_b2 = (const float*)d_in[6];
    const float* zm_w  = (const float*)d_in[7];
    const float* zm_b  = (const float*)d_in[8];
    const float* zl_w  = (const float*)d_in[9];
    const float* zl_b  = (const float*)d_in[10];
    const float* gw1   = (const float*)d_in[11];
    const float* gw2   = (const float*)d_in[12];
    const float* gb2   = (const float*)d_in[13];
    const float* colw  = (const float*)d_in[14];
    const float* colb  = (const float*)d_in[15];
    float* out = (float*)d_out;
    char* ws = (char*)d_ws;

    // workspace layout (bytes)
    ushort_t* gw1f = (ushort_t*)(ws + 0);          //  19,456 B
    ushort_t* gw2f = (ushort_t*)(ws + 19456);      // 194,560 B -> 214,016
    ushort_t* w1hi = (ushort_t*)(ws + 214016);     // 311,296 B -> 525,312
    ushort_t* w1lo = (ushort_t*)(ws + 525312);     // 311,296 B -> 836,608
    ushort_t* w2hi = (ushort_t*)(ws + 836608);     // 194,560 B -> 1,031,168
    ushort_t* w2lo = (ushort_t*)(ws + 1031168);    // 194,560 B -> 1,225,728
    ushort_t* w3hi = (ushort_t*)(ws + 1225728);    //  40,960 B -> 1,266,688
    ushort_t* w3lo = (ushort_t*)(ws + 1266688);    //  40,960 B -> 1,307,648
    float*    h1   = (float*)(ws + 1307648);       // 622,592 B -> 1,930,240  [512][304] f32
    float*    h2   = (float*)(ws + 214016);        // 622,592 B (overlaps dead w1hi/w1lo)
    float*    zb   = (float*)(ws + 1930240);       //  65,536 B -> 1,995,776  [512][32] f32

    prep_kernel<<<743, 64, 0, stream>>>(gw1, gw2, qz_w1, qz_w2, zm_w, zl_w,
                                        gw1f, gw2f, w1hi, w1lo, w2hi, w2lo, w3hi, w3lo);
    enc_gemm_f32<16, true><<<dim3(32, 5), 256, 0, stream>>>(
        x, 512, w1hi, w1lo, qz_b1, h1, 304, 300, NT);
    enc_gemm_f32<10, true><<<dim3(32, 5), 256, 0, stream>>>(
        h1, 304, w2hi, w2lo, qz_b2, h2, 304, 300, NT);
    enc3_reparam<<<32, 256, 0, stream>>>(h2, w3hi, w3lo, zm_b, zl_b, eps, out, zb);
    decode_kernel<<<dim3(8, 512), 512, 0, stream>>>(zb, Wm, gw1f, gw2f, gb2, colw, colb, out);
}

// Round 7
// 124.137 us; speedup vs baseline: 2.1372x; 1.0249x over previous
//
#include <hip/hip_runtime.h>

#define B_ 512
#define D_ 512
#define L_ 32
#define H_ 300
#define NT 19       // 16-col n-tiles of H
#define NS 10       // 32-k steps over K=300 (zero-padded weights beyond 300)
#define G1S 308     // g1 LDS row stride (ushorts): <=2-way on stores+reads (measured 0)

typedef unsigned short ushort_t;
typedef __bf16 bf16x8 __attribute__((ext_vector_type(8)));
typedef float f32x4 __attribute__((ext_vector_type(4)));

union B8 { ushort_t u[8]; uint4 q; bf16x8 v; uint2 d[2]; __bf16 b[8]; };

__device__ __forceinline__ void split8(const float* fv, B8& hi, B8& lo) {
    #pragma unroll
    for (int i = 0; i < 8; ++i) {
        __bf16 h = (__bf16)fv[i];
        hi.b[i] = h;
        lo.b[i] = (__bf16)(fv[i] - (float)h);
    }
}

// ---------------- prep: swizzle weights into MFMA B-fragment layout ----------------
// frag elem i of lane l = B[k = 32*s + 8*(l>>4) + i][n = 16*nt + (l&15)]; OOR -> 0
// decoder weights: single bf16; encoder weights: hi/lo bf16 pair (split-fp32)
__global__ __launch_bounds__(64) void prep_kernel(
        const float* __restrict__ gw1, const float* __restrict__ gw2,
        const float* __restrict__ qw1, const float* __restrict__ qw2,
        const float* __restrict__ zmw, const float* __restrict__ zlw,
        ushort_t* __restrict__ gw1f, ushort_t* __restrict__ gw2f,
        ushort_t* __restrict__ w1hi, ushort_t* __restrict__ w1lo,
        ushort_t* __restrict__ w2hi, ushort_t* __restrict__ w2lo,
        ushort_t* __restrict__ w3hi, ushort_t* __restrict__ w3lo) {
    int blk = blockIdx.x;
    int l = threadIdx.x, grp = l >> 4, li = l & 15;
    if (blk < 209) {    // decoder weights, single bf16
        const float* src; int K, nt, s; ushort_t* dst;
        if (blk < 19) { nt = blk; s = 0; src = gw1; K = 32; dst = gw1f + (nt * 64 + l) * 8; }
        else { int i = blk - 19; nt = i / 10; s = i % 10; src = gw2; K = 300;
               dst = gw2f + ((nt * 10 + s) * 64 + l) * 8; }
        int n = nt * 16 + li;
        B8 V;
        #pragma unroll
        for (int i = 0; i < 8; ++i) {
            int k = 32 * s + 8 * grp + i;
            V.b[i] = (__bf16)((k < K && n < H_) ? src[k * H_ + n] : 0.f);
        }
        *reinterpret_cast<uint4*>(dst) = V.q;
    } else {            // encoder weights, hi/lo split
        const float* src = nullptr; int K, N, nt, s, stacked = 0;
        ushort_t *dh, *dl;
        if (blk < 513)      { int i = blk - 209; nt = i / 16; s = i % 16; src = qw1; K = 512; N = 300;
                              dh = w1hi + ((nt * 16 + s) * 64 + l) * 8; dl = w1lo + ((nt * 16 + s) * 64 + l) * 8; }
        else if (blk < 703) { int i = blk - 513; nt = i / 10; s = i % 10; src = qw2; K = 300; N = 300;
                              dh = w2hi + ((nt * 10 + s) * 64 + l) * 8; dl = w2lo + ((nt * 10 + s) * 64 + l) * 8; }
        else                { int i = blk - 703; nt = i / 10; s = i % 10; K = 300; N = 64; stacked = 1;
                              dh = w3hi + ((nt * 10 + s) * 64 + l) * 8; dl = w3lo + ((nt * 10 + s) * 64 + l) * 8; }
        int n = nt * 16 + li;
        float fv[8];
        #pragma unroll
        for (int i = 0; i < 8; ++i) {
            int k = 32 * s + 8 * grp + i;
            float v = 0.f;
            if (k < K && n < N) {
                if (!stacked) v = src[k * N + n];
                else          v = (n < 32) ? zmw[k * 32 + n] : zlw[k * 32 + (n - 32)];
            }
            fv[i] = v;
        }
        B8 Vh, Vl;
        split8(fv, Vh, Vl);
        *reinterpret_cast<uint4*>(dh) = Vh.q;
        *reinterpret_cast<uint4*>(dl) = Vl.q;
    }
}

// ------------- encoder GEMM, split-bf16 (~fp32 accuracy): out = act(A @ W + bias) -------
// grid (M/16, ceil(N/64)); block = 16 rows, wave w owns n-tile blockIdx.y*4 + w
template<int KSTEPS, bool RELU>
__global__ __launch_bounds__(256) void enc_gemm_f32(const float* __restrict__ A, int lda,
        const ushort_t* __restrict__ Whi, const ushort_t* __restrict__ Wlo,
        const float* __restrict__ bias, float* __restrict__ out, int ldo,
        int Ncols, int ntiles) {
    const int tid = threadIdx.x;
    const int w = tid >> 6, lane = tid & 63;
    const int grp = lane >> 4, li = lane & 15;
    const int r0 = blockIdx.x * 16;
    const int nt = blockIdx.y * 4 + w;
    const bool active = nt < ntiles;

    f32x4 acc = {0.f, 0.f, 0.f, 0.f};
    for (int s = 0; s < KSTEPS; ++s) {
        int kb = 32 * s + 8 * grp;
        B8 Ah, Al;
        if (kb + 8 <= lda) {
            const float* ap = A + (size_t)(r0 + li) * lda + kb;
            float4 f0 = *reinterpret_cast<const float4*>(ap);
            float4 f1 = *reinterpret_cast<const float4*>(ap + 4);
            float fv[8] = {f0.x, f0.y, f0.z, f0.w, f1.x, f1.y, f1.z, f1.w};
            split8(fv, Ah, Al);
        } else {
            Ah.q = make_uint4(0, 0, 0, 0);
            Al.q = make_uint4(0, 0, 0, 0);
        }
        if (active) {
            bf16x8 bh = *reinterpret_cast<const bf16x8*>(
                Whi + ((size_t)(nt * KSTEPS + s) * 64 + lane) * 8);
            bf16x8 bl = *reinterpret_cast<const bf16x8*>(
                Wlo + ((size_t)(nt * KSTEPS + s) * 64 + lane) * 8);
            acc = __builtin_amdgcn_mfma_f32_16x16x32_bf16(Ah.v, bh, acc, 0, 0, 0);
            acc = __builtin_amdgcn_mfma_f32_16x16x32_bf16(Al.v, bh, acc, 0, 0, 0);
            acc = __builtin_amdgcn_mfma_f32_16x16x32_bf16(Ah.v, bl, acc, 0, 0, 0);
        }
    }
    if (active) {
        int h = nt * 16 + li;
        float bv = (bias != nullptr && h < Ncols) ? bias[h] : 0.f;
        #pragma unroll
        for (int r = 0; r < 4; ++r) {
            float v = acc[r] + bv;
            if (RELU) v = fmaxf(v, 0.f);
            if (h >= Ncols) v = 0.f;
            out[(size_t)(r0 + 4 * grp + r) * ldo + h] = v;
        }
    }
}

// -------- latent head (split-bf16) + reparameterize, fused: zm|zl = h2 @ w3; z = ... -----
__global__ __launch_bounds__(256) void enc3_reparam(const float* __restrict__ h2,
        const ushort_t* __restrict__ w3hi, const ushort_t* __restrict__ w3lo,
        const float* __restrict__ zmb, const float* __restrict__ zlb,
        const float* __restrict__ eps, float* __restrict__ out, float* __restrict__ zb) {
    __shared__ float zs[16][64];
    const int tid = threadIdx.x;
    const int w = tid >> 6, lane = tid & 63;
    const int grp = lane >> 4, li = lane & 15;
    const int r0 = blockIdx.x * 16;

    f32x4 acc = {0.f, 0.f, 0.f, 0.f};
    for (int s = 0; s < 10; ++s) {
        int kb = 32 * s + 8 * grp;
        B8 Ah, Al;
        if (kb + 8 <= 304) {
            const float* ap = h2 + (size_t)(r0 + li) * 304 + kb;
            float4 f0 = *reinterpret_cast<const float4*>(ap);
            float4 f1 = *reinterpret_cast<const float4*>(ap + 4);
            float fv[8] = {f0.x, f0.y, f0.z, f0.w, f1.x, f1.y, f1.z, f1.w};
            split8(fv, Ah, Al);
        } else {
            Ah.q = make_uint4(0, 0, 0, 0);
            Al.q = make_uint4(0, 0, 0, 0);
        }
        bf16x8 bh = *reinterpret_cast<const bf16x8*>(w3hi + ((size_t)(w * 10 + s) * 64 + lane) * 8);
        bf16x8 bl = *reinterpret_cast<const bf16x8*>(w3lo + ((size_t)(w * 10 + s) * 64 + lane) * 8);
        acc = __builtin_amdgcn_mfma_f32_16x16x32_bf16(Ah.v, bh, acc, 0, 0, 0);
        acc = __builtin_amdgcn_mfma_f32_16x16x32_bf16(Al.v, bh, acc, 0, 0, 0);
        acc = __builtin_amdgcn_mfma_f32_16x16x32_bf16(Ah.v, bl, acc, 0, 0, 0);
    }
    #pragma unroll
    for (int r = 0; r < 4; ++r) zs[4 * grp + r][w * 16 + li] = acc[r];
    __syncthreads();

    for (int idx = tid; idx < 512; idx += 256) {
        int m = idx >> 5, l2 = idx & 31;
        int row = r0 + m;
        float zm = zs[m][l2] + zmb[l2];
        float zl = zs[m][32 + l2] + zlb[l2];
        float zv = zm + eps[row * 32 + l2] * expf(0.5f * zl);
        out[B_ * D_ + row * 32 + l2] = zv;
        out[B_ * D_ + B_ * L_ + row * 32 + l2] = zm;
        out[B_ * D_ + 2 * B_ * L_ + row * 32 + l2] = zl;
        zb[row * 32 + l2] = zv;
    }
}

// ---------------- decoder: one block = (column j, 64 batch rows), 8 waves ----------------
// wave w owns n-tiles {w, w+8, w+16(if w<3)}; acc[4 m-tiles][<=3 n-tiles] = 48 AGPRs
__global__ __launch_bounds__(512, 4) void decode_kernel(
        const float* __restrict__ z, const float* __restrict__ Wmask,
        const ushort_t* __restrict__ gw1f, const ushort_t* __restrict__ gw2f,
        const float* __restrict__ gb2, const float* __restrict__ colw,
        const float* __restrict__ colb, float* __restrict__ xmean) {
    __shared__ __align__(16) ushort_t g1s[64 * G1S + 16];    // 39,456 B
    __shared__ float xpart[8][64];                           //  2,048 B

    const int j    = blockIdx.y;
    const int b0   = blockIdx.x * 64;
    const int tid  = threadIdx.x;
    const int w    = tid >> 6;
    const int lane = tid & 63;
    const int grp  = lane >> 4, li = lane & 15;
    const int ntl  = (w < 3) ? 3 : 2;             // n-tiles this wave: w, w+8, (w+16)

    // phase 0: masked B-frags in registers (all 4 m-tiles, per wave); zero pads
    B8 bm[4];
    {
        const float* wp = Wmask + (size_t)j * L_ + 8 * grp;
        float4 w0 = *reinterpret_cast<const float4*>(wp);
        float4 w1 = *reinterpret_cast<const float4*>(wp + 4);
        float wv[8] = {w0.x, w0.y, w0.z, w0.w, w1.x, w1.y, w1.z, w1.w};
        #pragma unroll
        for (int mt = 0; mt < 4; ++mt) {
            const float* zp = z + (size_t)(b0 + mt * 16 + li) * L_ + 8 * grp;
            float4 z0 = *reinterpret_cast<const float4*>(zp);
            float4 z1 = *reinterpret_cast<const float4*>(zp + 4);
            float zv[8] = {z0.x, z0.y, z0.z, z0.w, z1.x, z1.y, z1.z, z1.w};
            #pragma unroll
            for (int i = 0; i < 8; ++i) bm[mt].b[i] = (__bf16)(wv[i] * zv[i]);
        }
        // zero A-pad cols 304..307 (never written by phase 1) + 16-elem tail:
        // phase-2 s=9 reads cols up to 319 -> spill into next row (finite g1) or tail,
        // multiplied by zero-padded (k>=300) gw2f B entries
        if (tid < 272) {
            if (tid < 256) g1s[(tid >> 2) * G1S + 304 + (tid & 3)] = 0;
            else           g1s[64 * G1S + (tid - 256)] = 0;
        }
    }
    __syncthreads();

    // phase 1 (swapped): D = gw1^T(A) x masked^T(B) -> lane holds g1[b=li][4 consec h]
    #pragma unroll
    for (int t = 0; t < 3; ++t) {
        if (t < ntl) {
            int nt = w + 8 * t;
            bf16x8 ga = *reinterpret_cast<const bf16x8*>(gw1f + (nt * 64 + lane) * 8);
            #pragma unroll
            for (int mt = 0; mt < 4; ++mt) {
                f32x4 c = {0.f, 0.f, 0.f, 0.f};
                c = __builtin_amdgcn_mfma_f32_16x16x32_bf16(ga, bm[mt].v, c, 0, 0, 0);
                // c[r] = g1[b = mt*16+li][h = nt*16 + 4*grp + r]
                B8 P;
                #pragma unroll
                for (int r = 0; r < 4; ++r) P.b[r] = (__bf16)fmaxf(c[r], 0.f);
                *reinterpret_cast<uint2*>(&g1s[(mt * 16 + li) * G1S + nt * 16 + 4 * grp]) = P.d[0];
            }
        }
    }
    __syncthreads();

    // phase 2: g2 = relu(g1 @ gw2 + gb2); B-frag ping-pong prefetch (no reg copies)
    {
        f32x4 acc[4][3];
        #pragma unroll
        for (int mt = 0; mt < 4; ++mt)
            #pragma unroll
            for (int t = 0; t < 3; ++t) acc[mt][t] = {0.f, 0.f, 0.f, 0.f};

        const size_t lane8 = (size_t)lane * 8;
        bf16x8 bc[3], bn[3];
        #pragma unroll
        for (int t = 0; t < 3; ++t)
            if (t < ntl)
                bc[t] = *reinterpret_cast<const bf16x8*>(
                    gw2f + (size_t)((w + 8 * t) * NS) * 512 + lane8);

        for (int s = 0; s < NS; s += 2) {
            // prefetch s+1 (NS even -> always valid)
            #pragma unroll
            for (int t = 0; t < 3; ++t)
                if (t < ntl)
                    bn[t] = *reinterpret_cast<const bf16x8*>(
                        gw2f + (size_t)((w + 8 * t) * NS + s + 1) * 512 + lane8);
            {
                B8 af[4];
                #pragma unroll
                for (int mt = 0; mt < 4; ++mt) {
                    const ushort_t* p = &g1s[(mt * 16 + li) * G1S + 32 * s + 8 * grp];
                    af[mt].d[0] = *reinterpret_cast<const uint2*>(p);
                    af[mt].d[1] = *reinterpret_cast<const uint2*>(p + 4);
                }
                #pragma unroll
                for (int t = 0; t < 3; ++t)
                    if (t < ntl)
                        #pragma unroll
                        for (int mt = 0; mt < 4; ++mt)
                            acc[mt][t] = __builtin_amdgcn_mfma_f32_16x16x32_bf16(
                                af[mt].v, bc[t], acc[mt][t], 0, 0, 0);
            }
            // prefetch s+2 (clamped to 0 on last iteration; loaded value unused)
            int s2 = (s + 2 < NS) ? (s + 2) : 0;
            #pragma unroll
            for (int t = 0; t < 3; ++t)
                if (t < ntl)
                    bc[t] = *reinterpret_cast<const bf16x8*>(
                        gw2f + (size_t)((w + 8 * t) * NS + s2) * 512 + lane8);
            {
                B8 af[4];
                #pragma unroll
                for (int mt = 0; mt < 4; ++mt) {
                    const ushort_t* p = &g1s[(mt * 16 + li) * G1S + 32 * (s + 1) + 8 * grp];
                    af[mt].d[0] = *reinterpret_cast<const uint2*>(p);
                    af[mt].d[1] = *reinterpret_cast<const uint2*>(p + 4);
                }
                #pragma unroll
                for (int t = 0; t < 3; ++t)
                    if (t < ntl)
                        #pragma unroll
                        for (int mt = 0; mt < 4; ++mt)
                            acc[mt][t] = __builtin_amdgcn_mfma_f32_16x16x32_bf16(
                                af[mt].v, bn[t], acc[mt][t], 0, 0, 0);
            }
        }

        // epilogue: relu(acc + gb2) * colw[j], reduce over h (li lanes), no atomics
        float partial[4][4] = {};
        #pragma unroll
        for (int t = 0; t < 3; ++t) {
            if (t < ntl) {
                int h = (w + 8 * t) * 16 + li;
                float bias = 0.f, fac = 0.f;
                if (h < H_) { bias = gb2[h]; fac = colw[j * H_ + h]; }
                #pragma unroll
                for (int mt = 0; mt < 4; ++mt)
                    #pragma unroll
                    for (int r = 0; r < 4; ++r)
                        partial[mt][r] += fmaxf(acc[mt][t][r] + bias, 0.f) * fac;
            }
        }
        #pragma unroll
        for (int mt = 0; mt < 4; ++mt)
            #pragma unroll
            for (int r = 0; r < 4; ++r) {
                float v = partial[mt][r];
                v += __shfl_xor(v, 1);
                v += __shfl_xor(v, 2);
                v += __shfl_xor(v, 4);
                v += __shfl_xor(v, 8);
                if (li == 0) xpart[w][mt * 16 + 4 * grp + r] = v;
            }
    }
    __syncthreads();

    if (tid < 64) {
        float v = colb[j];
        #pragma unroll
        for (int ww = 0; ww < 8; ++ww) v += xpart[ww][tid];
        xmean[(size_t)(b0 + tid) * D_ + j] = v;
    }
}

extern "C" void kernel_launch(void* const* d_in, const int* in_sizes, int n_in,
                              void* d_out, int out_size, void* d_ws, size_t ws_size,
                              hipStream_t stream) {
    const float* x     = (const float*)d_in[0];
    const float* eps   = (const float*)d_in[1];
    const float* Wm    = (const float*)d_in[2];
    const float* qz_w1 = (const float*)d_in[3];
    const float* qz_b1 = (const float*)d_in[4];
    const float* qz_w2 = (const float*)d_in[5];
    const float* qz_b2 = (const float*)d_in[6];
    const float* zm_w  = (const float*)d_in[7];
    const float* zm_b  = (const float*)d_in[8];
    const float* zl_w  = (const float*)d_in[9];
    const float* zl_b  = (const float*)d_in[10];
    const float* gw1   = (const float*)d_in[11];
    const float* gw2   = (const float*)d_in[12];
    const float* gb2   = (const float*)d_in[13];
    const float* colw  = (const float*)d_in[14];
    const float* colb  = (const float*)d_in[15];
    float* out = (float*)d_out;
    char* ws = (char*)d_ws;

    // workspace layout (bytes)
    ushort_t* gw1f = (ushort_t*)(ws + 0);          //  19,456 B
    ushort_t* gw2f = (ushort_t*)(ws + 19456);      // 194,560 B -> 214,016
    ushort_t* w1hi = (ushort_t*)(ws + 214016);     // 311,296 B -> 525,312
    ushort_t* w1lo = (ushort_t*)(ws + 525312);     // 311,296 B -> 836,608
    ushort_t* w2hi = (ushort_t*)(ws + 836608);     // 194,560 B -> 1,031,168
    ushort_t* w2lo = (ushort_t*)(ws + 1031168);    // 194,560 B -> 1,225,728
    ushort_t* w3hi = (ushort_t*)(ws + 1225728);    //  40,960 B -> 1,266,688
    ushort_t* w3lo = (ushort_t*)(ws + 1266688);    //  40,960 B -> 1,307,648
    float*    h1   = (float*)(ws + 1307648);       // 622,592 B -> 1,930,240  [512][304] f32
    float*    h2   = (float*)(ws + 214016);        // 622,592 B (overlaps dead w1hi/w1lo)
    float*    zb   = (float*)(ws + 1930240);       //  65,536 B -> 1,995,776  [512][32] f32

    prep_kernel<<<743, 64, 0, stream>>>(gw1, gw2, qz_w1, qz_w2, zm_w, zl_w,
                                        gw1f, gw2f, w1hi, w1lo, w2hi, w2lo, w3hi, w3lo);
    enc_gemm_f32<16, true><<<dim3(32, 5), 256, 0, stream>>>(
        x, 512, w1hi, w1lo, qz_b1, h1, 304, 300, NT);
    enc_gemm_f32<10, true><<<dim3(32, 5), 256, 0, stream>>>(
        h1, 304, w2hi, w2lo, qz_b2, h2, 304, 300, NT);
    enc3_reparam<<<32, 256, 0, stream>>>(h2, w3hi, w3lo, zm_b, zl_b, eps, out, zb);
    decode_kernel<<<dim3(8, 512), 512, 0, stream>>>(zb, Wm, gw1f, gw2f, gb2, colw, colb, out);
}

// Round 8
// 111.782 us; speedup vs baseline: 2.3734x; 1.1105x over previous
//
#include <hip/hip_runtime.h>

#define B_ 512
#define D_ 512
#define L_ 32
#define H_ 300
#define NT 19       // 16-col n-tiles of H
#define NS 10       // 32-k steps over K=300 (zero-padded weights beyond 300)
#define G1S 308     // g1 LDS row stride (ushorts): <=2-way on stores+reads (measured 0)

typedef unsigned short ushort_t;
typedef __bf16 bf16x8 __attribute__((ext_vector_type(8)));
typedef float f32x4 __attribute__((ext_vector_type(4)));

union B8 { ushort_t u[8]; uint4 q; bf16x8 v; uint2 d[2]; __bf16 b[8]; };

__device__ __forceinline__ void split8(const float* fv, B8& hi, B8& lo) {
    #pragma unroll
    for (int i = 0; i < 8; ++i) {
        __bf16 h = (__bf16)fv[i];
        hi.b[i] = h;
        lo.b[i] = (__bf16)(fv[i] - (float)h);
    }
}

// ---------------- prep: swizzle weights into MFMA B-fragment layout ----------------
// frag elem i of lane l = B[k = 32*s + 8*(l>>4) + i][n = 16*nt + (l&15)]; OOR -> 0
// decoder weights: single bf16; encoder weights: hi/lo bf16 pair (split-fp32)
__global__ __launch_bounds__(64) void prep_kernel(
        const float* __restrict__ gw1, const float* __restrict__ gw2,
        const float* __restrict__ qw1, const float* __restrict__ qw2,
        const float* __restrict__ zmw, const float* __restrict__ zlw,
        ushort_t* __restrict__ gw1f, ushort_t* __restrict__ gw2f,
        ushort_t* __restrict__ w1hi, ushort_t* __restrict__ w1lo,
        ushort_t* __restrict__ w2hi, ushort_t* __restrict__ w2lo,
        ushort_t* __restrict__ w3hi, ushort_t* __restrict__ w3lo) {
    int blk = blockIdx.x;
    int l = threadIdx.x, grp = l >> 4, li = l & 15;
    if (blk < 209) {    // decoder weights, single bf16
        const float* src; int K, nt, s; ushort_t* dst;
        if (blk < 19) { nt = blk; s = 0; src = gw1; K = 32; dst = gw1f + (nt * 64 + l) * 8; }
        else { int i = blk - 19; nt = i / 10; s = i % 10; src = gw2; K = 300;
               dst = gw2f + ((nt * 10 + s) * 64 + l) * 8; }
        int n = nt * 16 + li;
        B8 V;
        #pragma unroll
        for (int i = 0; i < 8; ++i) {
            int k = 32 * s + 8 * grp + i;
            V.b[i] = (__bf16)((k < K && n < H_) ? src[k * H_ + n] : 0.f);
        }
        *reinterpret_cast<uint4*>(dst) = V.q;
    } else {            // encoder weights, hi/lo split
        const float* src = nullptr; int K, N, nt, s, stacked = 0;
        ushort_t *dh, *dl;
        if (blk < 513)      { int i = blk - 209; nt = i / 16; s = i % 16; src = qw1; K = 512; N = 300;
                              dh = w1hi + ((nt * 16 + s) * 64 + l) * 8; dl = w1lo + ((nt * 16 + s) * 64 + l) * 8; }
        else if (blk < 703) { int i = blk - 513; nt = i / 10; s = i % 10; src = qw2; K = 300; N = 300;
                              dh = w2hi + ((nt * 10 + s) * 64 + l) * 8; dl = w2lo + ((nt * 10 + s) * 64 + l) * 8; }
        else                { int i = blk - 703; nt = i / 10; s = i % 10; K = 300; N = 64; stacked = 1;
                              dh = w3hi + ((nt * 10 + s) * 64 + l) * 8; dl = w3lo + ((nt * 10 + s) * 64 + l) * 8; }
        int n = nt * 16 + li;
        float fv[8];
        #pragma unroll
        for (int i = 0; i < 8; ++i) {
            int k = 32 * s + 8 * grp + i;
            float v = 0.f;
            if (k < K && n < N) {
                if (!stacked) v = src[k * N + n];
                else          v = (n < 32) ? zmw[k * 32 + n] : zlw[k * 32 + (n - 32)];
            }
            fv[i] = v;
        }
        B8 Vh, Vl;
        split8(fv, Vh, Vl);
        *reinterpret_cast<uint4*>(dh) = Vh.q;
        *reinterpret_cast<uint4*>(dl) = Vl.q;
    }
}

// ------------- encoder GEMM, split-bf16 (~fp32 accuracy): out = act(A @ W + bias) -------
// grid (M/16, ceil(N/64)); block = 16 rows, wave w owns n-tile blockIdx.y*4 + w
template<int KSTEPS, bool RELU>
__global__ __launch_bounds__(256) void enc_gemm_f32(const float* __restrict__ A, int lda,
        const ushort_t* __restrict__ Whi, const ushort_t* __restrict__ Wlo,
        const float* __restrict__ bias, float* __restrict__ out, int ldo,
        int Ncols, int ntiles) {
    const int tid = threadIdx.x;
    const int w = tid >> 6, lane = tid & 63;
    const int grp = lane >> 4, li = lane & 15;
    const int r0 = blockIdx.x * 16;
    const int nt = blockIdx.y * 4 + w;
    const bool active = nt < ntiles;

    f32x4 acc = {0.f, 0.f, 0.f, 0.f};
    for (int s = 0; s < KSTEPS; ++s) {
        int kb = 32 * s + 8 * grp;
        B8 Ah, Al;
        if (kb + 8 <= lda) {
            const float* ap = A + (size_t)(r0 + li) * lda + kb;
            float4 f0 = *reinterpret_cast<const float4*>(ap);
            float4 f1 = *reinterpret_cast<const float4*>(ap + 4);
            float fv[8] = {f0.x, f0.y, f0.z, f0.w, f1.x, f1.y, f1.z, f1.w};
            split8(fv, Ah, Al);
        } else {
            Ah.q = make_uint4(0, 0, 0, 0);
            Al.q = make_uint4(0, 0, 0, 0);
        }
        if (active) {
            bf16x8 bh = *reinterpret_cast<const bf16x8*>(
                Whi + ((size_t)(nt * KSTEPS + s) * 64 + lane) * 8);
            bf16x8 bl = *reinterpret_cast<const bf16x8*>(
                Wlo + ((size_t)(nt * KSTEPS + s) * 64 + lane) * 8);
            acc = __builtin_amdgcn_mfma_f32_16x16x32_bf16(Ah.v, bh, acc, 0, 0, 0);
            acc = __builtin_amdgcn_mfma_f32_16x16x32_bf16(Al.v, bh, acc, 0, 0, 0);
            acc = __builtin_amdgcn_mfma_f32_16x16x32_bf16(Ah.v, bl, acc, 0, 0, 0);
        }
    }
    if (active) {
        int h = nt * 16 + li;
        float bv = (bias != nullptr && h < Ncols) ? bias[h] : 0.f;
        #pragma unroll
        for (int r = 0; r < 4; ++r) {
            float v = acc[r] + bv;
            if (RELU) v = fmaxf(v, 0.f);
            if (h >= Ncols) v = 0.f;
            out[(size_t)(r0 + 4 * grp + r) * ldo + h] = v;
        }
    }
}

// -------- latent head (split-bf16) + reparameterize, fused: zm|zl = h2 @ w3; z = ... -----
__global__ __launch_bounds__(256) void enc3_reparam(const float* __restrict__ h2,
        const ushort_t* __restrict__ w3hi, const ushort_t* __restrict__ w3lo,
        const float* __restrict__ zmb, const float* __restrict__ zlb,
        const float* __restrict__ eps, float* __restrict__ out, float* __restrict__ zb) {
    __shared__ float zs[16][64];
    const int tid = threadIdx.x;
    const int w = tid >> 6, lane = tid & 63;
    const int grp = lane >> 4, li = lane & 15;
    const int r0 = blockIdx.x * 16;

    f32x4 acc = {0.f, 0.f, 0.f, 0.f};
    for (int s = 0; s < 10; ++s) {
        int kb = 32 * s + 8 * grp;
        B8 Ah, Al;
        if (kb + 8 <= 304) {
            const float* ap = h2 + (size_t)(r0 + li) * 304 + kb;
            float4 f0 = *reinterpret_cast<const float4*>(ap);
            float4 f1 = *reinterpret_cast<const float4*>(ap + 4);
            float fv[8] = {f0.x, f0.y, f0.z, f0.w, f1.x, f1.y, f1.z, f1.w};
            split8(fv, Ah, Al);
        } else {
            Ah.q = make_uint4(0, 0, 0, 0);
            Al.q = make_uint4(0, 0, 0, 0);
        }
        bf16x8 bh = *reinterpret_cast<const bf16x8*>(w3hi + ((size_t)(w * 10 + s) * 64 + lane) * 8);
        bf16x8 bl = *reinterpret_cast<const bf16x8*>(w3lo + ((size_t)(w * 10 + s) * 64 + lane) * 8);
        acc = __builtin_amdgcn_mfma_f32_16x16x32_bf16(Ah.v, bh, acc, 0, 0, 0);
        acc = __builtin_amdgcn_mfma_f32_16x16x32_bf16(Al.v, bh, acc, 0, 0, 0);
        acc = __builtin_amdgcn_mfma_f32_16x16x32_bf16(Ah.v, bl, acc, 0, 0, 0);
    }
    #pragma unroll
    for (int r = 0; r < 4; ++r) zs[4 * grp + r][w * 16 + li] = acc[r];
    __syncthreads();

    for (int idx = tid; idx < 512; idx += 256) {
        int m = idx >> 5, l2 = idx & 31;
        int row = r0 + m;
        float zm = zs[m][l2] + zmb[l2];
        float zl = zs[m][32 + l2] + zlb[l2];
        float zv = zm + eps[row * 32 + l2] * expf(0.5f * zl);
        out[B_ * D_ + row * 32 + l2] = zv;
        out[B_ * D_ + B_ * L_ + row * 32 + l2] = zm;
        out[B_ * D_ + 2 * B_ * L_ + row * 32 + l2] = zl;
        zb[row * 32 + l2] = zv;
    }
}

// ---------------- decoder: one block = (column j, 64 batch rows), 4 waves ----------------
// wave w owns n-tiles w*5..w*5+4 (w=3: 4) and ALL 4 m-tiles: 20 MFMA per af-set
__global__ __launch_bounds__(256, 3) void decode_kernel(
        const float* __restrict__ z, const float* __restrict__ Wmask,
        const ushort_t* __restrict__ gw1f, const ushort_t* __restrict__ gw2f,
        const float* __restrict__ gb2, const float* __restrict__ colw,
        const float* __restrict__ colb, float* __restrict__ xmean) {
    __shared__ __align__(16) ushort_t g1s[64 * G1S + 16];    // 39,456 B
    __shared__ float xpart[4][64];                           //  1,024 B

    const int j    = blockIdx.y;
    const int b0   = blockIdx.x * 64;
    const int tid  = threadIdx.x;
    const int w    = tid >> 6;
    const int lane = tid & 63;
    const int grp  = lane >> 4, li = lane & 15;
    const int nlocal = (w == 3) ? 4 : 5;          // n-tiles 19 = 5+5+5+4 across waves

    // phase 0: masked B-frags in registers (all 4 m-tiles, per wave); zero pads
    B8 bm[4];
    {
        const float* wp = Wmask + (size_t)j * L_ + 8 * grp;
        float4 w0 = *reinterpret_cast<const float4*>(wp);
        float4 w1 = *reinterpret_cast<const float4*>(wp + 4);
        float wv[8] = {w0.x, w0.y, w0.z, w0.w, w1.x, w1.y, w1.z, w1.w};
        #pragma unroll
        for (int mt = 0; mt < 4; ++mt) {
            const float* zp = z + (size_t)(b0 + mt * 16 + li) * L_ + 8 * grp;
            float4 z0 = *reinterpret_cast<const float4*>(zp);
            float4 z1 = *reinterpret_cast<const float4*>(zp + 4);
            float zv[8] = {z0.x, z0.y, z0.z, z0.w, z1.x, z1.y, z1.z, z1.w};
            #pragma unroll
            for (int i = 0; i < 8; ++i) bm[mt].b[i] = (__bf16)(wv[i] * zv[i]);
        }
        // zero A-pad cols 304..307 (never written by phase 1) + 16-elem tail:
        // phase-2 s=9 reads cols up to 319 -> spill into next row (finite g1) or tail,
        // multiplied by zero-padded (k>=300) gw2f B entries
        for (int idx = tid; idx < 272; idx += 256) {
            if (idx < 256) g1s[(idx >> 2) * G1S + 304 + (idx & 3)] = 0;
            else           g1s[64 * G1S + (idx - 256)] = 0;
        }
    }
    __syncthreads();

    // phase 1 (swapped): D = gw1^T(A) x masked^T(B) -> lane holds g1[b=li][4 consec h]
    #pragma unroll
    for (int ntl = 0; ntl < 5; ++ntl) {
        if (ntl < nlocal) {
            int nt = w * 5 + ntl;
            bf16x8 ga = *reinterpret_cast<const bf16x8*>(gw1f + (nt * 64 + lane) * 8);
            #pragma unroll
            for (int mt = 0; mt < 4; ++mt) {
                f32x4 c = {0.f, 0.f, 0.f, 0.f};
                c = __builtin_amdgcn_mfma_f32_16x16x32_bf16(ga, bm[mt].v, c, 0, 0, 0);
                // c[r] = g1[b = mt*16+li][h = nt*16 + 4*grp + r]
                B8 P;
                #pragma unroll
                for (int r = 0; r < 4; ++r) P.b[r] = (__bf16)fmaxf(c[r], 0.f);
                *reinterpret_cast<uint2*>(&g1s[(mt * 16 + li) * G1S + nt * 16 + 4 * grp]) = P.d[0];
            }
        }
    }
    __syncthreads();

    // phase 2: g2 = relu(g1 @ gw2 + gb2); af reused across 5 n-tiles (20 MFMA/af-set)
    {
        f32x4 acc[4][5];
        #pragma unroll
        for (int mt = 0; mt < 4; ++mt)
            #pragma unroll
            for (int n = 0; n < 5; ++n) acc[mt][n] = {0.f, 0.f, 0.f, 0.f};

        const size_t lane8 = (size_t)lane * 8;
        for (int s = 0; s < NS; ++s) {
            B8 af[4];
            #pragma unroll
            for (int mt = 0; mt < 4; ++mt) {
                const ushort_t* p = &g1s[(mt * 16 + li) * G1S + 32 * s + 8 * grp];
                af[mt].d[0] = *reinterpret_cast<const uint2*>(p);
                af[mt].d[1] = *reinterpret_cast<const uint2*>(p + 4);
            }
            #pragma unroll
            for (int ntl = 0; ntl < 5; ++ntl) {
                if (ntl < nlocal) {
                    bf16x8 bfr = *reinterpret_cast<const bf16x8*>(
                        gw2f + (size_t)((w * 5 + ntl) * NS + s) * 512 + lane8);
                    #pragma unroll
                    for (int mt = 0; mt < 4; ++mt)
                        acc[mt][ntl] = __builtin_amdgcn_mfma_f32_16x16x32_bf16(
                            af[mt].v, bfr, acc[mt][ntl], 0, 0, 0);
                }
            }
        }

        // epilogue: relu(acc + gb2) * colw[j], reduce over h (li lanes), no atomics
        float partial[4][4] = {};
        #pragma unroll
        for (int ntl = 0; ntl < 5; ++ntl) {
            if (ntl < nlocal) {
                int h = (w * 5 + ntl) * 16 + li;
                float bias = 0.f, fac = 0.f;
                if (h < H_) { bias = gb2[h]; fac = colw[j * H_ + h]; }
                #pragma unroll
                for (int mt = 0; mt < 4; ++mt)
                    #pragma unroll
                    for (int r = 0; r < 4; ++r)
                        partial[mt][r] += fmaxf(acc[mt][ntl][r] + bias, 0.f) * fac;
            }
        }
        #pragma unroll
        for (int mt = 0; mt < 4; ++mt)
            #pragma unroll
            for (int r = 0; r < 4; ++r) {
                float v = partial[mt][r];
                v += __shfl_xor(v, 1);
                v += __shfl_xor(v, 2);
                v += __shfl_xor(v, 4);
                v += __shfl_xor(v, 8);
                if (li == 0) xpart[w][mt * 16 + 4 * grp + r] = v;
            }
    }
    __syncthreads();

    if (tid < 64) {
        float v = colb[j];
        #pragma unroll
        for (int ww = 0; ww < 4; ++ww) v += xpart[ww][tid];
        xmean[(size_t)(b0 + tid) * D_ + j] = v;
    }
}

extern "C" void kernel_launch(void* const* d_in, const int* in_sizes, int n_in,
                              void* d_out, int out_size, void* d_ws, size_t ws_size,
                              hipStream_t stream) {
    const float* x     = (const float*)d_in[0];
    const float* eps   = (const float*)d_in[1];
    const float* Wm    = (const float*)d_in[2];
    const float* qz_w1 = (const float*)d_in[3];
    const float* qz_b1 = (const float*)d_in[4];
    const float* qz_w2 = (const float*)d_in[5];
    const float* qz_b2 = (const float*)d_in[6];
    const float* zm_w  = (const float*)d_in[7];
    const float* zm_b  = (const float*)d_in[8];
    const float* zl_w  = (const float*)d_in[9];
    const float* zl_b  = (const float*)d_in[10];
    const float* gw1   = (const float*)d_in[11];
    const float* gw2   = (const float*)d_in[12];
    const float* gb2   = (const float*)d_in[13];
    const float* colw  = (const float*)d_in[14];
    const float* colb  = (const float*)d_in[15];
    float* out = (float*)d_out;
    char* ws = (char*)d_ws;

    // workspace layout (bytes)
    ushort_t* gw1f = (ushort_t*)(ws + 0);          //  19,456 B
    ushort_t* gw2f = (ushort_t*)(ws + 19456);      // 194,560 B -> 214,016
    ushort_t* w1hi = (ushort_t*)(ws + 214016);     // 311,296 B -> 525,312
    ushort_t* w1lo = (ushort_t*)(ws + 525312);     // 311,296 B -> 836,608
    ushort_t* w2hi = (ushort_t*)(ws + 836608);     // 194,560 B -> 1,031,168
    ushort_t* w2lo = (ushort_t*)(ws + 1031168);    // 194,560 B -> 1,225,728
    ushort_t* w3hi = (ushort_t*)(ws + 1225728);    //  40,960 B -> 1,266,688
    ushort_t* w3lo = (ushort_t*)(ws + 1266688);    //  40,960 B -> 1,307,648
    float*    h1   = (float*)(ws + 1307648);       // 622,592 B -> 1,930,240  [512][304] f32
    float*    h2   = (float*)(ws + 214016);        // 622,592 B (overlaps dead w1hi/w1lo)
    float*    zb   = (float*)(ws + 1930240);       //  65,536 B -> 1,995,776  [512][32] f32

    prep_kernel<<<743, 64, 0, stream>>>(gw1, gw2, qz_w1, qz_w2, zm_w, zl_w,
                                        gw1f, gw2f, w1hi, w1lo, w2hi, w2lo, w3hi, w3lo);
    enc_gemm_f32<16, true><<<dim3(32, 5), 256, 0, stream>>>(
        x, 512, w1hi, w1lo, qz_b1, h1, 304, 300, NT);
    enc_gemm_f32<10, true><<<dim3(32, 5), 256, 0, stream>>>(
        h1, 304, w2hi, w2lo, qz_b2, h2, 304, 300, NT);
    enc3_reparam<<<32, 256, 0, stream>>>(h2, w3hi, w3lo, zm_b, zl_b, eps, out, zb);
    decode_kernel<<<dim3(8, 512), 256, 0, stream>>>(zb, Wm, gw1f, gw2f, gb2, colw, colb, out);
}